// Round 10
// baseline (472.676 us; speedup 1.0000x reference)
//
#include <hip/hip_runtime.h>
#include <stdint.h>

#define HID 128

typedef __attribute__((ext_vector_type(8))) short bf16x8;
typedef __attribute__((ext_vector_type(4))) float f32x4;

__device__ __forceinline__ float bf2f(unsigned short u){
  union { unsigned int i; float f; } x; x.i = ((unsigned int)u) << 16; return x.f;
}
__device__ __forceinline__ unsigned short f2bf(float f){
  union { float f; unsigned int i; } x; x.f = f;
  unsigned int b = x.i;
  return (unsigned short)((b + 0x7fffu + ((b >> 16) & 1u)) >> 16);
}

// ---------------- setup: dtype flag + weight conv + x->bf16 + deg_count ----------
struct CvList {
  const void* src[16];
  float* dst[16];
  int cnt[16];
  int n;
};
__global__ __launch_bounds__(256) void setup(CvList L, const void* x,
                                             unsigned short* xc, int n4,
                                             int* __restrict__ dflag,
                                             const int* __restrict__ ei, int E,
                                             int* __restrict__ deg){
  __shared__ int red[4];
  int tid = threadIdx.x;
  const unsigned short* xs = (const unsigned short*)x;
  unsigned short u = xs[tid];
  int ex = (u >> 7) & 0xFF;
  int v = ((((tid & 1) == 0) && u == 0) ? 1 : 0) | ((ex >= 140) ? 65536 : 0);
  #pragma unroll
  for (int m = 1; m < 64; m <<= 1) v += __shfl_xor(v, m);
  if ((tid & 63) == 0) red[tid >> 6] = v;
  __syncthreads();
  int tot = red[0] + red[1] + red[2] + red[3];
  bool isf32 = ((tot & 0xffff) >= 32) || ((tot >> 16) >= 8);
  if (blockIdx.x == 0 && tid == 0) dflag[0] = isf32 ? 1 : 0;
  // degree count (whole grid)
  int e = blockIdx.x*256 + tid;
  if (e < E) atomicAdd(&deg[ei[E + e]], 1);
  // weights + x conversion (whole grid)
  int gstride = gridDim.x*256;
  int gid = blockIdx.x*256 + tid;
  for (int a = 0; a < L.n; ++a){
    const void* s = L.src[a];
    float* d = L.dst[a];
    int c = L.cnt[a];
    for (int i = gid; i < c; i += gstride)
      d[i] = isf32 ? ((const float*)s)[i] : bf2f(((const unsigned short*)s)[i]);
  }
  for (int i = gid; i < n4; i += gstride){
    if (isf32){
      float4 q = ((const float4*)x)[i];
      ushort4 o; o.x = f2bf(q.x); o.y = f2bf(q.y); o.z = f2bf(q.z); o.w = f2bf(q.w);
      ((ushort4*)xc)[i] = o;
    } else {
      ((ushort4*)xc)[i] = ((const ushort4*)x)[i];
    }
  }
}

// ---------------- precompute M = W_bond @ (W_edge @ att_edge), cbias = b_bond @ ve ----
__global__ __launch_bounds__(256) void precompute_M(
    const float* __restrict__ We, const float* __restrict__ ae,
    const float* __restrict__ Wb, const float* __restrict__ bb,
    float* __restrict__ Mout, float* __restrict__ cb)
{
  __shared__ float ve[128*12];
  int tid = threadIdx.x;
  for (int i = tid; i < 128*12; i += 256){
    int c = i / 12, lh = i % 12; int l = lh >> 2, h = lh & 3;
    float s = 0.f;
    for (int d = 0; d < 32; ++d)
      s += We[l*16384 + c*128 + h*32 + d] * ae[l*128 + h*32 + d];
    ve[i] = s;
  }
  __syncthreads();
  for (int i = tid; i < 16*12; i += 256){
    int k = i / 12, lh = i % 12;
    float s = 0.f;
    for (int c = 0; c < 128; ++c) s += Wb[k*128 + c] * ve[c*12 + lh];
    Mout[i] = s;
  }
  for (int i = tid; i < 12; i += 256){
    float s = 0.f;
    for (int c = 0; c < 128; ++c) s += bb[c] * ve[c*12 + i];
    cb[i] = s;
  }
}

// ---------------- CSR build ----------------
__global__ __launch_bounds__(256) void scan_part(const int* __restrict__ deg, int* __restrict__ part, int N){
  int base = blockIdx.x*1024;
  int s = 0;
  for (int i = threadIdx.x; i < 1024; i += 256){ int j = base + i; if (j < N) s += deg[j]; }
  __shared__ int sh[256];
  sh[threadIdx.x] = s; __syncthreads();
  for (int m = 128; m > 0; m >>= 1){ if (threadIdx.x < m) sh[threadIdx.x] += sh[threadIdx.x + m]; __syncthreads(); }
  if (threadIdx.x == 0) part[blockIdx.x] = sh[0];
}
__global__ void scan_top(int* part, int P){
  if (threadIdx.x == 0 && blockIdx.x == 0){
    int acc = 0;
    for (int i = 0; i < P; ++i){ int v = part[i]; part[i] = acc; acc += v; }
  }
}
// also emits dinv[n] = {deg>0 ? 1 : 0, 1/max(deg,1)}
__global__ __launch_bounds__(256) void scan_write(const int* __restrict__ deg, const int* __restrict__ part,
                                                  int* __restrict__ row, float2* __restrict__ dinv,
                                                  int N, int E){
  int base = blockIdx.x*1024 + threadIdx.x*4;
  int v0=0,v1=0,v2=0,v3=0;
  if (base+0 < N) v0 = deg[base+0];
  if (base+1 < N) v1 = deg[base+1];
  if (base+2 < N) v2 = deg[base+2];
  if (base+3 < N) v3 = deg[base+3];
  int s = v0+v1+v2+v3;
  __shared__ int sh[256];
  sh[threadIdx.x] = s; __syncthreads();
  for (int m = 1; m < 256; m <<= 1){
    int t = (threadIdx.x >= m) ? sh[threadIdx.x - m] : 0;
    __syncthreads();
    sh[threadIdx.x] += t;
    __syncthreads();
  }
  int excl = sh[threadIdx.x] - s + part[blockIdx.x];
  if (base+0 < N){ row[base+0] = excl; float2 q; q.x = v0>0?1.f:0.f; q.y = 1.f/(float)(v0>0?v0:1); dinv[base+0]=q; } excl += v0;
  if (base+1 < N){ row[base+1] = excl; float2 q; q.x = v1>0?1.f:0.f; q.y = 1.f/(float)(v1>0?v1:1); dinv[base+1]=q; } excl += v1;
  if (base+2 < N){ row[base+2] = excl; float2 q; q.x = v2>0?1.f:0.f; q.y = 1.f/(float)(v2>0?v2:1); dinv[base+2]=q; } excl += v2;
  if (base+3 < N){ row[base+3] = excl; float2 q; q.x = v3>0?1.f:0.f; q.y = 1.f/(float)(v3>0?v3:1); dinv[base+3]=q; }
  if (blockIdx.x == 0 && threadIdx.x == 0) row[N] = E;
}

// ---------------- proj_fill: 4 edges/thread (independent chains for latency hiding) ----
// record (32 B): words 0..5 = proj[0..11] as bf16 pairs (lh = l*4+h), word6 = src, word7 = dst
__device__ __forceinline__ void proj_one(int e, int E,
                                         const int* __restrict__ ei,
                                         const int* __restrict__ row, int* __restrict__ cursor,
                                         const void* __restrict__ eattr,
                                         const float (*sM)[12],
                                         uint4* __restrict__ rec, int* __restrict__ perm,
                                         bool isf32){
  if (e >= E) return;
  int s = ei[e], d = ei[E + e];
  float v[16];
  if (isf32){
    const float4* pp = (const float4*)((const float*)eattr + (size_t)e*16);
    float4 a = pp[0], b = pp[1], c = pp[2], dd = pp[3];
    v[0]=a.x; v[1]=a.y; v[2]=a.z; v[3]=a.w;
    v[4]=b.x; v[5]=b.y; v[6]=b.z; v[7]=b.w;
    v[8]=c.x; v[9]=c.y; v[10]=c.z; v[11]=c.w;
    v[12]=dd.x; v[13]=dd.y; v[14]=dd.z; v[15]=dd.w;
  } else {
    const uint4* pp = (const uint4*)((const unsigned short*)eattr + (size_t)e*16);
    uint4 a = pp[0], b = pp[1];
    unsigned w[8] = {a.x,a.y,a.z,a.w,b.x,b.y,b.z,b.w};
    #pragma unroll
    for (int j = 0; j < 8; ++j){
      v[2*j]   = bf2f((unsigned short)(w[j] & 0xffffu));
      v[2*j+1] = bf2f((unsigned short)(w[j] >> 16));
    }
  }
  float p[12];
  #pragma unroll
  for (int j = 0; j < 12; ++j){
    float acc = 0.f;
    #pragma unroll
    for (int k = 0; k < 16; ++k) acc += v[k]*sM[k][j];
    p[j] = acc;
  }
  uint4 q0, q1;
  q0.x = (unsigned)f2bf(p[0])  | ((unsigned)f2bf(p[1])  << 16);
  q0.y = (unsigned)f2bf(p[2])  | ((unsigned)f2bf(p[3])  << 16);
  q0.z = (unsigned)f2bf(p[4])  | ((unsigned)f2bf(p[5])  << 16);
  q0.w = (unsigned)f2bf(p[6])  | ((unsigned)f2bf(p[7])  << 16);
  q1.x = (unsigned)f2bf(p[8])  | ((unsigned)f2bf(p[9])  << 16);
  q1.y = (unsigned)f2bf(p[10]) | ((unsigned)f2bf(p[11]) << 16);
  q1.z = (unsigned)s; q1.w = (unsigned)d;
  rec[(size_t)e*2]   = q0;   // coalesced, edge order
  rec[(size_t)e*2+1] = q1;
  int pos = atomicAdd(&cursor[d], 1);
  perm[row[d] + pos] = e;    // only 4 B scattered
}
__global__ __launch_bounds__(256) void proj_fill(const int* __restrict__ ei, int E,
                                                 const int* __restrict__ row, int* __restrict__ cursor,
                                                 const void* __restrict__ eattr,
                                                 const float* __restrict__ Mmat,
                                                 uint4* __restrict__ rec, int* __restrict__ perm,
                                                 const int* __restrict__ flag){
  __shared__ float sM[16][12];
  int tid = threadIdx.x;
  if (tid < 192) sM[tid/12][tid%12] = Mmat[tid];
  __syncthreads();
  bool isf32 = flag[0] != 0;
  int e0 = blockIdx.x*1024 + tid;
  proj_one(e0,       E, ei, row, cursor, eattr, sM, rec, perm, isf32);
  proj_one(e0 + 256, E, ei, row, cursor, eattr, sM, rec, perm, isf32);
  proj_one(e0 + 512, E, ei, row, cursor, eattr, sM, rec, perm, isf32);
  proj_one(e0 + 768, E, ei, row, cursor, eattr, sM, rec, perm, isf32);
}

// ---------------- per-node mean of projected edge terms: 4 lanes/node ----------
__global__ __launch_bounds__(256) void mean_proj_k(const uint4* __restrict__ rec,
                                                   const int* __restrict__ perm,
                                                   const int* __restrict__ row,
                                                   const float2* __restrict__ dinv,
                                                   float* __restrict__ mp, int N){
  int idx = blockIdx.x*256 + threadIdx.x;
  int n = idx >> 2, q = idx & 3;
  if (n >= N) return;
  int r = row[n], deg = row[n+1] - r;
  float acc[12] = {};
  for (int e = q; e < deg; e += 4){
    int ed = perm[r + e];
    uint4 a = rec[(size_t)ed*2];
    uint2 b = *(const uint2*)(rec + (size_t)ed*2 + 1);
    unsigned w[6] = {a.x,a.y,a.z,a.w,b.x,b.y};
    #pragma unroll
    for (int j = 0; j < 6; ++j){
      acc[2*j]   += bf2f((unsigned short)(w[j] & 0xffffu));
      acc[2*j+1] += bf2f((unsigned short)(w[j] >> 16));
    }
  }
  #pragma unroll
  for (int m = 1; m < 4; m <<= 1){
    #pragma unroll
    for (int j = 0; j < 12; ++j) acc[j] += __shfl_xor(acc[j], m);
  }
  if (q == 0){
    float inv = dinv[n].x > 0.f ? dinv[n].y : 1.f;
    float* op = mp + (size_t)n*12;
    float4 o0, o1, o2;
    o0.x=acc[0]*inv; o0.y=acc[1]*inv; o0.z=acc[2]*inv; o0.w=acc[3]*inv;
    o1.x=acc[4]*inv; o1.y=acc[5]*inv; o1.z=acc[6]*inv; o1.w=acc[7]*inv;
    o2.x=acc[8]*inv; o2.y=acc[9]*inv; o2.z=acc[10]*inv; o2.w=acc[11]*inv;
    *(float4*)(op)   = o0;
    *(float4*)(op+4) = o1;
    *(float4*)(op+8) = o2;
  }
}

__device__ __forceinline__ float lrelu(float x){ return x > 0.f ? x : 0.2f*x; }
__device__ __forceinline__ float expg(float x){ return __expf(fminf(x, 0.f)); }

// shared EPI: attention scores + self-loop alpha, from acc[8] C-fragments
// mpL = mproj + layer*4 (stride 12 floats per node, MEANS; dinv.x = deg>0 indicator)
template<typename ACC>
__device__ __forceinline__ void att_epi(const ACC* acc, int m, int quad, int nodeBase, int N,
                                        const float* sAs, const float* sAd,
                                        const float* sCB,
                                        const float* __restrict__ mpL,
                                        const float2* __restrict__ dinv,
                                        float* __restrict__ a_src,
                                        float* __restrict__ a_dst,
                                        float* __restrict__ alpha_self)
{
  #pragma unroll
  for (int r2 = 0; r2 < 4; ++r2){
    float vs[4], vd[4];
    #pragma unroll
    for (int h = 0; h < 4; ++h){
      int c0 = (2*h)*16 + m, c1 = (2*h+1)*16 + m;
      vs[h] = acc[2*h][r2]*sAs[c0] + acc[2*h+1][r2]*sAs[c1];
      vd[h] = acc[2*h][r2]*sAd[c0] + acc[2*h+1][r2]*sAd[c1];
    }
    #pragma unroll
    for (int mm = 1; mm < 16; mm <<= 1){
      #pragma unroll
      for (int h = 0; h < 4; ++h){
        vs[h] += __shfl_xor(vs[h], mm);
        vd[h] += __shfl_xor(vd[h], mm);
      }
    }
    if (m == 0){
      int nd = nodeBase + quad*4 + r2;
      if (nd < N){
        float2 di = dinv[nd];
        float4 mp4 = *(const float4*)(mpL + (size_t)nd*12);
        float mpv[4] = {mp4.x, mp4.y, mp4.z, mp4.w};
        float aS[4];
        #pragma unroll
        for (int h = 0; h < 4; ++h)
          aS[h] = lrelu(vs[h] + vd[h] + sCB[h]*di.x + mpv[h]);
        float4 vsv, vdv, asv;
        vsv.x=vs[0]; vsv.y=vs[1]; vsv.z=vs[2]; vsv.w=vs[3];
        vdv.x=vd[0]; vdv.y=vd[1]; vdv.z=vd[2]; vdv.w=vd[3];
        asv.x=aS[0]; asv.y=aS[1]; asv.z=aS[2]; asv.w=aS[3];
        *(float4*)(a_src + (size_t)nd*4) = vsv;
        *(float4*)(a_dst + (size_t)nd*4) = vdv;
        *(float4*)(alpha_self + (size_t)nd*4) = asv;
      }
    }
  }
}

// ---------------- MFMA GEMM: out[N,128] = A[N,K](bf16) @ W[K,128] (+bias) ----------------
// OUTMODE: 0 = bf16 out (+EPI), 2 = dual fp32 + bf16 (no EPI)
template<int K, int OUTMODE, bool EPI>
__global__ __launch_bounds__(256) void mfma_lin(const unsigned short* __restrict__ A,
                                                const float* __restrict__ W,
                                                const float* __restrict__ bias,
                                                void* __restrict__ Out, void* __restrict__ Out2,
                                                int N,
                                                const float* __restrict__ attS,
                                                const float* __restrict__ attD,
                                                const float* __restrict__ cbl,
                                                const float* __restrict__ mpL,
                                                const float2* __restrict__ dinv,
                                                float* __restrict__ a_src,
                                                float* __restrict__ a_dst,
                                                float* __restrict__ alpha_self)
{
  constexpr int KP = K + 8;
  __shared__ unsigned short WT[128*KP];
  __shared__ float sAs[128], sAd[128];
  __shared__ float sCB[4];
  int tid = threadIdx.x;
  for (int i = tid; i < K*128; i += 256){
    int k = i >> 7, ch = i & 127;
    WT[ch*KP + k] = f2bf(W[i]);
  }
  if (EPI){
    if (tid < 128){ sAs[tid] = attS[tid]; sAd[tid] = attD[tid]; }
    if (tid < 4)  sCB[tid] = cbl[tid];
  }
  __syncthreads();
  int wid = tid >> 6, lane = tid & 63;
  int quad = lane >> 4, m = lane & 15;
  int nodeBase = blockIdx.x*64 + wid*16;
  int node = nodeBase + m;
  int nodeC = (node < N) ? node : 0;
  bf16x8 afr[K/32];
  #pragma unroll
  for (int kb = 0; kb < K/32; ++kb)
    afr[kb] = *(const bf16x8*)(A + (size_t)nodeC*K + kb*32 + quad*8);
  f32x4 acc[8] = {};
  #pragma unroll
  for (int t = 0; t < 8; ++t){
    #pragma unroll
    for (int kb = 0; kb < K/32; ++kb){
      bf16x8 bfr = *(const bf16x8*)&WT[(t*16 + m)*KP + kb*32 + quad*8];
      acc[t] = __builtin_amdgcn_mfma_f32_16x16x32_bf16(afr[kb], bfr, acc[t], 0, 0, 0);
    }
  }
  #pragma unroll
  for (int t = 0; t < 8; ++t){
    int ch = t*16 + m;
    float bv = bias ? bias[ch] : 0.f;
    #pragma unroll
    for (int r2 = 0; r2 < 4; ++r2){
      int nd = nodeBase + quad*4 + r2;
      if (nd < N){
        float v = acc[t][r2] + bv;
        if (OUTMODE == 0){
          ((unsigned short*)Out)[(size_t)nd*HID + ch] = f2bf(v);
        } else {
          ((float*)Out)[(size_t)nd*HID + ch] = v;
          ((unsigned short*)Out2)[(size_t)nd*HID + ch] = f2bf(v);
        }
      }
    }
  }
  if (EPI)
    att_epi(acc, m, quad, nodeBase, N, sAs, sAd, sCB,
            mpL, dinv, a_src, a_dst, alpha_self);
}

// ---------------- fused BN + ReLU + residual + GEMM (+EPI / external out) -------------
// hg is bf16 (GAT output). OUTMODE 0: bf16 xh out + EPI + fp32 h out; 1: external out
// bnsum/bnsq are 64-way BANKED: [64][128]; prologue reduces the banks.
template<int OUTMODE, bool WRITEH>
__global__ __launch_bounds__(256) void bn_mfma(const unsigned short* __restrict__ hg,
                                               const float* __restrict__ hprev,
                                               const float* __restrict__ bnsum,
                                               const float* __restrict__ bnsq,
                                               const float* __restrict__ gamma,
                                               const float* __restrict__ beta,
                                               const float* __restrict__ W,
                                               const float* __restrict__ bias,
                                               void* __restrict__ Out,
                                               float* __restrict__ hout,
                                               int N, const int* __restrict__ flag,
                                               const float* __restrict__ attS,
                                               const float* __restrict__ attD,
                                               const float* __restrict__ cbl,
                                               const float* __restrict__ mpL,
                                               const float2* __restrict__ dinv,
                                               float* __restrict__ a_src,
                                               float* __restrict__ a_dst,
                                               float* __restrict__ alpha_self)
{
  constexpr int K = 128, KP = 136;
  __shared__ unsigned short WT[128*KP];
  __shared__ float sSc[128], sSh[128];
  __shared__ float sAs[128], sAd[128];
  __shared__ float sCB[4];
  int tid = threadIdx.x;
  for (int i = tid; i < K*128; i += 256){
    int k = i >> 7, ch = i & 127;
    WT[ch*KP + k] = f2bf(W[i]);
  }
  if (tid < 128){
    float s = 0.f, q = 0.f;
    #pragma unroll 8
    for (int b = 0; b < 64; ++b){
      s += bnsum[b*128 + tid];
      q += bnsq[b*128 + tid];
    }
    float mean = s / (float)N;
    float var  = fmaxf(q / (float)N - mean*mean, 0.f);
    float sc = gamma[tid] * rsqrtf(var + 1e-5f);
    sSc[tid] = sc;
    sSh[tid] = beta[tid] - mean*sc;
    if (OUTMODE == 0){ sAs[tid] = attS[tid]; sAd[tid] = attD[tid]; }
  }
  if (OUTMODE == 0){
    if (tid < 4)  sCB[tid] = cbl[tid];
  }
  __syncthreads();
  int wid = tid >> 6, lane = tid & 63;
  int quad = lane >> 4, m = lane & 15;
  int nodeBase = blockIdx.x*64 + wid*16;
  int node = nodeBase + m;
  int nodeC = (node < N) ? node : 0;
  bf16x8 afr[4];
  #pragma unroll
  for (int kb = 0; kb < 4; ++kb){
    int cbase = kb*32 + quad*8;
    uint4 gu = *(const uint4*)(hg + (size_t)nodeC*K + cbase);
    const float4* pp = (const float4*)(hprev + (size_t)nodeC*K + cbase);
    float4 p0 = pp[0], p1 = pp[1];
    unsigned gw[4] = {gu.x, gu.y, gu.z, gu.w};
    float pv[8] = {p0.x,p0.y,p0.z,p0.w,p1.x,p1.y,p1.z,p1.w};
    float r[8];
    #pragma unroll
    for (int j = 0; j < 8; ++j){
      float g = bf2f((unsigned short)((j & 1) ? (gw[j>>1] >> 16) : (gw[j>>1] & 0xffffu)));
      float t = g*sSc[cbase+j] + sSh[cbase+j];
      t = t > 0.f ? t : 0.f;
      r[j] = t + pv[j];
    }
    if (WRITEH && node < N){
      float4 o0, o1;
      o0.x=r[0]; o0.y=r[1]; o0.z=r[2]; o0.w=r[3];
      o1.x=r[4]; o1.y=r[5]; o1.z=r[6]; o1.w=r[7];
      float4* hp = (float4*)(hout + (size_t)node*K + cbase);
      hp[0] = o0; hp[1] = o1;
    }
    bf16x8 f;
    #pragma unroll
    for (int j = 0; j < 8; ++j) f[j] = (short)f2bf(r[j]);
    afr[kb] = f;
  }
  f32x4 acc[8] = {};
  #pragma unroll
  for (int t = 0; t < 8; ++t){
    #pragma unroll
    for (int kb = 0; kb < 4; ++kb){
      bf16x8 bfr = *(const bf16x8*)&WT[(t*16 + m)*KP + kb*32 + quad*8];
      acc[t] = __builtin_amdgcn_mfma_f32_16x16x32_bf16(afr[kb], bfr, acc[t], 0, 0, 0);
    }
  }
  bool f32out = (OUTMODE == 1) && (flag[0] != 0);
  #pragma unroll
  for (int t = 0; t < 8; ++t){
    int ch = t*16 + m;
    float bv = bias ? bias[ch] : 0.f;
    #pragma unroll
    for (int r2 = 0; r2 < 4; ++r2){
      int nd = nodeBase + quad*4 + r2;
      if (nd < N){
        float v = acc[t][r2] + bv;
        if (OUTMODE == 0) ((unsigned short*)Out)[(size_t)nd*HID + ch] = f2bf(v);
        else if (f32out)  ((float*)Out)[(size_t)nd*HID + ch] = v;
        else              ((unsigned short*)Out)[(size_t)nd*HID + ch] = f2bf(v);
      }
    }
  }
  if (OUTMODE == 0)
    att_epi(acc, m, quad, nodeBase, N, sAs, sAd, sCB,
            mpL, dinv, a_src, a_dst, alpha_self);
}

// ---- inline per-edge alpha: perm -> record gather -> lrelu(as + ad + proj[layer]) ----
__device__ __forceinline__ float4 edge_alpha4(const unsigned* __restrict__ recw,
                                              const int* __restrict__ perm, int pos,
                                              const float* __restrict__ a_src,
                                              float4 adn, int layer, int* src_out){
  int e0 = perm[pos];
  const unsigned* rp = recw + (size_t)e0*8;
  unsigned w0 = rp[2*layer], w1 = rp[2*layer+1];
  int s = (int)rp[6];
  float4 as4 = *(const float4*)(a_src + (size_t)s*4);
  float4 o;
  o.x = lrelu(as4.x + adn.x + bf2f((unsigned short)(w0 & 0xffffu)));
  o.y = lrelu(as4.y + adn.y + bf2f((unsigned short)(w0 >> 16)));
  o.z = lrelu(as4.z + adn.z + bf2f((unsigned short)(w1 & 0xffffu)));
  o.w = lrelu(as4.w + adn.w + bf2f((unsigned short)(w1 >> 16)));
  *src_out = s;
  return o;
}

__device__ __forceinline__ void acc2(unsigned u, float q, float& a0, float& a1){
  union { unsigned i; float f; } lo, hi;
  lo.i = u << 16; hi.i = u & 0xffff0000u;
  a0 += q*lo.f; a1 += q*hi.f;
}

// ---------------- GAT aggregation: 32 lanes/node (2 nodes/wave), fused BN stats ----
__global__ __launch_bounds__(256) void gat_agg(
    const unsigned short* __restrict__ xh,
    const uint4* __restrict__ rec, const int* __restrict__ perm,
    const int* __restrict__ row,
    const float* __restrict__ a_src, const float* __restrict__ a_dst,
    const float4* __restrict__ alpha_self,
    const float* __restrict__ bconv, unsigned short* __restrict__ hout,
    float* __restrict__ bnsumB, float* __restrict__ bnsqB,
    int N, int layer)
{
  __shared__ float sPf[8][256];      // [node][e*4+h]
  __shared__ int   sOff[8][64];
  __shared__ float sBS[8][128];      // per-node channel sums
  __shared__ float sBQ[8][128];      // per-node channel squares
  int tid = threadIdx.x;
  int wid = tid >> 6, lane = tid & 63;
  int half = lane >> 5, sl = lane & 31;
  int g = wid*2 + half;
  int n = blockIdx.x*8 + g;
  int nn = (n < N) ? n : 0;
  int r = row[nn];
  int deg = row[nn+1] - r;
  if (n >= N) deg = 0;
  const unsigned* recw = (const unsigned*)rec;

  float4 adn = *(const float4*)(a_dst + (size_t)nn*4);
  float4 aA; aA.x = aA.y = aA.z = aA.w = -1e30f;
  float4 aB; aB.x = aB.y = aB.z = aB.w = -1e30f;
  int sA = 0, sB = 0;
  if (sl < deg)      aA = edge_alpha4(recw, perm, r + sl,      a_src, adn, layer, &sA);
  if (32 + sl < deg) aB = edge_alpha4(recw, perm, r + 32 + sl, a_src, adn, layer, &sB);
  float mx0 = fmaxf(aA.x, aB.x), mx1 = fmaxf(aA.y, aB.y);
  float mx2 = fmaxf(aA.z, aB.z), mx3 = fmaxf(aA.w, aB.w);
  for (int e = 64 + sl; e < deg; e += 32){   // rare (deg>64)
    int st;
    float4 a4 = edge_alpha4(recw, perm, r + e, a_src, adn, layer, &st);
    mx0 = fmaxf(mx0, a4.x); mx1 = fmaxf(mx1, a4.y);
    mx2 = fmaxf(mx2, a4.z); mx3 = fmaxf(mx3, a4.w);
  }
  #pragma unroll
  for (int m = 1; m < 32; m <<= 1){
    mx0 = fmaxf(mx0, __shfl_xor(mx0,m)); mx1 = fmaxf(mx1, __shfl_xor(mx1,m));
    mx2 = fmaxf(mx2, __shfl_xor(mx2,m)); mx3 = fmaxf(mx3, __shfl_xor(mx3,m));
  }
  float4 sf = alpha_self[nn];
  mx0 = fmaxf(mx0, sf.x); mx1 = fmaxf(mx1, sf.y);
  mx2 = fmaxf(mx2, sf.z); mx3 = fmaxf(mx3, sf.w);

  float d0 = 0.f, d1 = 0.f, d2 = 0.f, d3 = 0.f;
  if (sl < deg){
    float4 p;
    p.x = expg(aA.x-mx0); p.y = expg(aA.y-mx1);
    p.z = expg(aA.z-mx2); p.w = expg(aA.w-mx3);
    *(float4*)&sPf[g][sl*4] = p;
    sOff[g][sl] = sA << 8;
    d0 = p.x; d1 = p.y; d2 = p.z; d3 = p.w;
  }
  if (32 + sl < deg){
    float4 p;
    p.x = expg(aB.x-mx0); p.y = expg(aB.y-mx1);
    p.z = expg(aB.z-mx2); p.w = expg(aB.w-mx3);
    *(float4*)&sPf[g][(32+sl)*4] = p;
    sOff[g][32+sl] = sB << 8;
    d0 += p.x; d1 += p.y; d2 += p.z; d3 += p.w;
  }
  for (int e = 64 + sl; e < deg; e += 32){   // rare
    int st;
    float4 a4 = edge_alpha4(recw, perm, r + e, a_src, adn, layer, &st);
    d0 += expg(a4.x-mx0); d1 += expg(a4.y-mx1);
    d2 += expg(a4.z-mx2); d3 += expg(a4.w-mx3);
  }
  #pragma unroll
  for (int m = 1; m < 32; m <<= 1){
    d0 += __shfl_xor(d0,m); d1 += __shfl_xor(d1,m); d2 += __shfl_xor(d2,m); d3 += __shfl_xor(d3,m);
  }
  float ps0 = expg(sf.x-mx0), ps1 = expg(sf.y-mx1), ps2 = expg(sf.z-mx2), ps3 = expg(sf.w-mx3);
  float i0 = 1.0f/(d0+ps0+1e-16f), i1 = 1.0f/(d1+ps1+1e-16f);
  float i2 = 1.0f/(d2+ps2+1e-16f), i3 = 1.0f/(d3+ps3+1e-16f);

  // gather: lane covers channels sl*4 .. sl*4+3; head h = sl>>3
  int h = sl >> 3;
  float mxh = h==0 ? mx0 : h==1 ? mx1 : h==2 ? mx2 : mx3;
  float ih  = h==0 ? i0  : h==1 ? i1  : h==2 ? i2  : i3;
  float psh = h==0 ? ps0 : h==1 ? ps1 : h==2 ? ps2 : ps3;
  const char* xb = (const char*)xh;
  float a0=0.f, a1=0.f, a2=0.f, a3=0.f;
  int dmin = deg < 64 ? deg : 64;
  int e = 0;
  for (; e + 4 <= dmin; e += 4){
    int oA = sOff[g][e+0], oB = sOff[g][e+1], oC = sOff[g][e+2], oD = sOff[g][e+3];
    float qA = sPf[g][(e+0)*4 + h], qB = sPf[g][(e+1)*4 + h];
    float qC = sPf[g][(e+2)*4 + h], qD = sPf[g][(e+3)*4 + h];
    uint2 xA = *(const uint2*)(xb + (size_t)oA + sl*8);
    uint2 xB = *(const uint2*)(xb + (size_t)oB + sl*8);
    uint2 xC = *(const uint2*)(xb + (size_t)oC + sl*8);
    uint2 xD = *(const uint2*)(xb + (size_t)oD + sl*8);
    acc2(xA.x, qA, a0,a1); acc2(xA.y, qA, a2,a3);
    acc2(xB.x, qB, a0,a1); acc2(xB.y, qB, a2,a3);
    acc2(xC.x, qC, a0,a1); acc2(xC.y, qC, a2,a3);
    acc2(xD.x, qD, a0,a1); acc2(xD.y, qD, a2,a3);
  }
  for (; e < dmin; ++e){
    int o = sOff[g][e];
    float q = sPf[g][e*4 + h];
    uint2 xv = *(const uint2*)(xb + (size_t)o + sl*8);
    acc2(xv.x, q, a0,a1); acc2(xv.y, q, a2,a3);
  }
  for (; e < deg; ++e){            // rare (deg>64): recompute alpha
    int st;
    float4 a4 = edge_alpha4(recw, perm, r + e, a_src, adn, layer, &st);
    float av = h==0 ? a4.x : h==1 ? a4.y : h==2 ? a4.z : a4.w;
    float q = expg(av - mxh);
    uint2 xv = *(const uint2*)(xb + (size_t)st*256 + sl*8);
    acc2(xv.x, q, a0,a1); acc2(xv.y, q, a2,a3);
  }
  float fo0=0.f, fo1=0.f, fo2=0.f, fo3=0.f;
  if (n < N){
    uint2 xn = *(const uint2*)(xb + (size_t)nn*256 + sl*8);
    acc2(xn.x, psh, a0,a1); acc2(xn.y, psh, a2,a3);
    float4 bc = *(const float4*)(bconv + layer*128 + sl*4);
    fo0 = a0*ih + bc.x; fo1 = a1*ih + bc.y;
    fo2 = a2*ih + bc.z; fo3 = a3*ih + bc.w;
    uint2 ov;
    ov.x = (unsigned)f2bf(fo0) | ((unsigned)f2bf(fo1) << 16);
    ov.y = (unsigned)f2bf(fo2) | ((unsigned)f2bf(fo3) << 16);
    *(uint2*)((char*)hout + (size_t)nn*256 + sl*8) = ov;
  }
  // fused BN stats: per-node channel partials in LDS, then banked atomics
  float4 vS; vS.x=fo0; vS.y=fo1; vS.z=fo2; vS.w=fo3;
  float4 vQ; vQ.x=fo0*fo0; vQ.y=fo1*fo1; vQ.z=fo2*fo2; vQ.w=fo3*fo3;
  *(float4*)&sBS[g][sl*4] = vS;
  *(float4*)&sBQ[g][sl*4] = vQ;
  __syncthreads();
  if (tid < 128){
    float ss = 0.f, qq = 0.f;
    #pragma unroll
    for (int k = 0; k < 8; ++k){ ss += sBS[k][tid]; qq += sBQ[k][tid]; }
    int bank = (blockIdx.x & 63) << 7;   // *128
    atomicAdd(&bnsumB[bank + tid], ss);
    atomicAdd(&bnsqB[bank + tid], qq);
  }
}

// ---------------- host ----------------
extern "C" void kernel_launch(void* const* d_in, const int* in_sizes, int n_in,
                              void* d_out, int out_size, void* d_ws, size_t ws_size,
                              hipStream_t stream)
{
  const void* x        = d_in[0];
  const int*  ei       = (const int*)d_in[1];
  const void* eattr    = d_in[2];
  int N = in_sizes[0] / 64;
  int E = in_sizes[1] / 2;

  char* p = (char*)d_ws;
  auto alloc = [&](size_t bytes)->char* {
    char* r = p; p += (bytes + 255) & ~(size_t)255; return r;
  };
  // zero-region first (one memset)
  int*   deg    = (int*)alloc((size_t)N*4);
  int*   cursor = (int*)alloc((size_t)N*4);
  float* bnsumB = (float*)alloc(3*64*128*4);   // banked BN partials
  float* bnsqB  = (float*)alloc(3*64*128*4);
  size_t zbytes = (size_t)(p - (char*)deg);
  int*   dflag  = (int*)alloc(256);
  int*   row    = (int*)alloc(((size_t)N + 1)*4);
  int*   part   = (int*)alloc(1024*4);
  uint4* rec    = (uint4*)alloc((size_t)E*32);
  int*   perm   = (int*)alloc((size_t)E*4);
  float* hA     = (float*)alloc((size_t)N*128*4);
  float* hB     = (float*)alloc((size_t)N*128*4);
  unsigned short* hGb = (unsigned short*)alloc((size_t)N*128*2);
  unsigned short* hAb = (unsigned short*)alloc((size_t)N*128*2);
  unsigned short* xhb = (unsigned short*)alloc((size_t)N*128*2);
  float* a_src  = (float*)alloc((size_t)N*4*4);
  float* a_dst  = (float*)alloc((size_t)N*4*4);
  float* alphaS = (float*)alloc((size_t)N*4*4);
  float* mproj  = (float*)alloc((size_t)N*12*4);
  float2* dinv  = (float2*)alloc((size_t)N*8);
  float* Mmat   = (float*)alloc(16*12*4);
  float* cbias  = (float*)alloc(12*4);
  unsigned short* xc  = (unsigned short*)alloc((size_t)N*64*2);
  float* wc     = (float*)alloc(130000*4);

  // canonical weight buffers (fp32)
  int   woff[14] = {0, 8192, 8320, 10368, 10496, 59648, 108800, 109184,
                    109568, 109952, 110336, 110720, 111104, 127488};
  int   wcnt[14] = {8192, 128, 2048, 128, 49152, 49152, 384, 384, 384, 384, 384, 384, 16384, 128};
  CvList L; L.n = 14;
  for (int a = 0; a < 14; ++a){ L.src[a] = d_in[3+a]; L.dst[a] = wc + woff[a]; L.cnt[a] = wcnt[a]; }
  float* cW_atom = wc + woff[0];  float* cb_atom = wc + woff[1];
  float* cW_bond = wc + woff[2];  float* cb_bond = wc + woff[3];
  float* cW_lin  = wc + woff[4];  float* cW_edge = wc + woff[5];
  float* catt_s  = wc + woff[6];  float* catt_d  = wc + woff[7];
  float* catt_e  = wc + woff[8];  float* cbconv  = wc + woff[9];
  float* cgamma  = wc + woff[10]; float* cbeta   = wc + woff[11];
  float* cW_out  = wc + woff[12]; float* cb_out  = wc + woff[13];

  hipMemsetAsync(deg, 0, zbytes, stream);
  setup<<<(E + 255)/256, 256, 0, stream>>>(L, x, xc, N*16, dflag, ei, E, deg);
  precompute_M<<<1, 256, 0, stream>>>(cW_edge, catt_e, cW_bond, cb_bond, Mmat, cbias);
  int P = (N + 1023)/1024;
  scan_part<<<P, 256, 0, stream>>>(deg, part, N);
  scan_top<<<1, 64, 0, stream>>>(part, P);
  scan_write<<<P, 256, 0, stream>>>(deg, part, row, dinv, N, E);
  proj_fill<<<(E + 1023)/1024, 256, 0, stream>>>(ei, E, row, cursor, eattr, Mmat, rec, perm, dflag);
  mean_proj_k<<<((size_t)N*4 + 255)/256, 256, 0, stream>>>(rec, perm, row, dinv, mproj, N);

  // atom embedding: hA(fp32) + hAb(bf16) = x @ W_atom + b_atom
  mfma_lin<64, 2, false><<<(N + 63)/64, 256, 0, stream>>>(xc, cW_atom, cb_atom, hA, hAb, N,
      nullptr, nullptr, nullptr, nullptr, nullptr, nullptr, nullptr, nullptr);
  // layer-0 GEMM + attention scores + self-loop alpha
  mfma_lin<128, 0, true><<<(N + 63)/64, 256, 0, stream>>>(hAb, cW_lin, nullptr, xhb, nullptr, N,
      catt_s, catt_d, cbias, mproj, dinv, a_src, a_dst, alphaS);

  float* cur = hA; float* oth = hB;
  for (int l = 0; l < 3; ++l){
    gat_agg<<<(N + 7)/8, 256, 0, stream>>>(xhb, rec, perm, row, a_src, a_dst,
                                           (const float4*)alphaS, cbconv, hGb,
                                           bnsumB + l*8192, bnsqB + l*8192, N, l);
    if (l < 2){
      bn_mfma<0, true><<<(N + 63)/64, 256, 0, stream>>>(hGb, cur,
          bnsumB + l*8192, bnsqB + l*8192, cgamma + l*128, cbeta + l*128,
          cW_lin + (size_t)(l+1)*16384, nullptr, xhb, oth, N, dflag,
          catt_s + (l+1)*128, catt_d + (l+1)*128, cbias + (l+1)*4,
          mproj + (l+1)*4, dinv, a_src, a_dst, alphaS);
      float* t = cur; cur = oth; oth = t;
    } else {
      bn_mfma<1, false><<<(N + 63)/64, 256, 0, stream>>>(hGb, cur,
          bnsumB + l*8192, bnsqB + l*8192, cgamma + l*128, cbeta + l*128,
          cW_out, cb_out, d_out, nullptr, N, dflag,
          nullptr, nullptr, nullptr, nullptr, nullptr, nullptr, nullptr, nullptr);
    }
  }
}

// Round 11
// 442.687 us; speedup vs baseline: 1.0677x; 1.0677x over previous
//
#include <hip/hip_runtime.h>
#include <stdint.h>

#define HID 128

typedef __attribute__((ext_vector_type(8))) short bf16x8;
typedef __attribute__((ext_vector_type(4))) float f32x4;

__device__ __forceinline__ float bf2f(unsigned short u){
  union { unsigned int i; float f; } x; x.i = ((unsigned int)u) << 16; return x.f;
}
__device__ __forceinline__ unsigned short f2bf(float f){
  union { float f; unsigned int i; } x; x.f = f;
  unsigned int b = x.i;
  return (unsigned short)((b + 0x7fffu + ((b >> 16) & 1u)) >> 16);
}

// ---------------- setup: dtype flag + weight conv + x->bf16 + deg_count + edge pos ----
// the deg-count atomic's RETURN VALUE is the edge's slot within its dst bucket ->
// store it (epos) so proj_fill needs no atomic at all.
struct CvList {
  const void* src[16];
  float* dst[16];
  int cnt[16];
  int n;
};
__global__ __launch_bounds__(256) void setup(CvList L, const void* x,
                                             unsigned short* xc, int n4,
                                             int* __restrict__ dflag,
                                             const int* __restrict__ ei, int E,
                                             int* __restrict__ deg,
                                             int* __restrict__ epos){
  __shared__ int red[4];
  int tid = threadIdx.x;
  const unsigned short* xs = (const unsigned short*)x;
  unsigned short u = xs[tid];
  int ex = (u >> 7) & 0xFF;
  int v = ((((tid & 1) == 0) && u == 0) ? 1 : 0) | ((ex >= 140) ? 65536 : 0);
  #pragma unroll
  for (int m = 1; m < 64; m <<= 1) v += __shfl_xor(v, m);
  if ((tid & 63) == 0) red[tid >> 6] = v;
  __syncthreads();
  int tot = red[0] + red[1] + red[2] + red[3];
  bool isf32 = ((tot & 0xffff) >= 32) || ((tot >> 16) >= 8);
  if (blockIdx.x == 0 && tid == 0) dflag[0] = isf32 ? 1 : 0;
  // degree count + slot capture (whole grid)
  int e = blockIdx.x*256 + tid;
  if (e < E) epos[e] = atomicAdd(&deg[ei[E + e]], 1);
  // weights + x conversion (whole grid)
  int gstride = gridDim.x*256;
  int gid = blockIdx.x*256 + tid;
  for (int a = 0; a < L.n; ++a){
    const void* s = L.src[a];
    float* d = L.dst[a];
    int c = L.cnt[a];
    for (int i = gid; i < c; i += gstride)
      d[i] = isf32 ? ((const float*)s)[i] : bf2f(((const unsigned short*)s)[i]);
  }
  for (int i = gid; i < n4; i += gstride){
    if (isf32){
      float4 q = ((const float4*)x)[i];
      ushort4 o; o.x = f2bf(q.x); o.y = f2bf(q.y); o.z = f2bf(q.z); o.w = f2bf(q.w);
      ((ushort4*)xc)[i] = o;
    } else {
      ((ushort4*)xc)[i] = ((const ushort4*)x)[i];
    }
  }
}

// ---------------- precompute M = W_bond @ (W_edge @ att_edge), cbias = b_bond @ ve ----
__global__ __launch_bounds__(256) void precompute_M(
    const float* __restrict__ We, const float* __restrict__ ae,
    const float* __restrict__ Wb, const float* __restrict__ bb,
    float* __restrict__ Mout, float* __restrict__ cb)
{
  __shared__ float ve[128*12];
  int tid = threadIdx.x;
  for (int i = tid; i < 128*12; i += 256){
    int c = i / 12, lh = i % 12; int l = lh >> 2, h = lh & 3;
    float s = 0.f;
    for (int d = 0; d < 32; ++d)
      s += We[l*16384 + c*128 + h*32 + d] * ae[l*128 + h*32 + d];
    ve[i] = s;
  }
  __syncthreads();
  for (int i = tid; i < 16*12; i += 256){
    int k = i / 12, lh = i % 12;
    float s = 0.f;
    for (int c = 0; c < 128; ++c) s += Wb[k*128 + c] * ve[c*12 + lh];
    Mout[i] = s;
  }
  for (int i = tid; i < 12; i += 256){
    float s = 0.f;
    for (int c = 0; c < 128; ++c) s += bb[c] * ve[c*12 + i];
    cb[i] = s;
  }
}

// ---------------- CSR build ----------------
__global__ __launch_bounds__(256) void scan_part(const int* __restrict__ deg, int* __restrict__ part, int N){
  int base = blockIdx.x*1024;
  int s = 0;
  for (int i = threadIdx.x; i < 1024; i += 256){ int j = base + i; if (j < N) s += deg[j]; }
  __shared__ int sh[256];
  sh[threadIdx.x] = s; __syncthreads();
  for (int m = 128; m > 0; m >>= 1){ if (threadIdx.x < m) sh[threadIdx.x] += sh[threadIdx.x + m]; __syncthreads(); }
  if (threadIdx.x == 0) part[blockIdx.x] = sh[0];
}
__global__ void scan_top(int* part, int P){
  if (threadIdx.x == 0 && blockIdx.x == 0){
    int acc = 0;
    for (int i = 0; i < P; ++i){ int v = part[i]; part[i] = acc; acc += v; }
  }
}
// also emits dinv[n] = {deg>0 ? 1 : 0, 1/max(deg,1)}
__global__ __launch_bounds__(256) void scan_write(const int* __restrict__ deg, const int* __restrict__ part,
                                                  int* __restrict__ row, float2* __restrict__ dinv,
                                                  int N, int E){
  int base = blockIdx.x*1024 + threadIdx.x*4;
  int v0=0,v1=0,v2=0,v3=0;
  if (base+0 < N) v0 = deg[base+0];
  if (base+1 < N) v1 = deg[base+1];
  if (base+2 < N) v2 = deg[base+2];
  if (base+3 < N) v3 = deg[base+3];
  int s = v0+v1+v2+v3;
  __shared__ int sh[256];
  sh[threadIdx.x] = s; __syncthreads();
  for (int m = 1; m < 256; m <<= 1){
    int t = (threadIdx.x >= m) ? sh[threadIdx.x - m] : 0;
    __syncthreads();
    sh[threadIdx.x] += t;
    __syncthreads();
  }
  int excl = sh[threadIdx.x] - s + part[blockIdx.x];
  if (base+0 < N){ row[base+0] = excl; float2 q; q.x = v0>0?1.f:0.f; q.y = 1.f/(float)(v0>0?v0:1); dinv[base+0]=q; } excl += v0;
  if (base+1 < N){ row[base+1] = excl; float2 q; q.x = v1>0?1.f:0.f; q.y = 1.f/(float)(v1>0?v1:1); dinv[base+1]=q; } excl += v1;
  if (base+2 < N){ row[base+2] = excl; float2 q; q.x = v2>0?1.f:0.f; q.y = 1.f/(float)(v2>0?v2:1); dinv[base+2]=q; } excl += v2;
  if (base+3 < N){ row[base+3] = excl; float2 q; q.x = v3>0?1.f:0.f; q.y = 1.f/(float)(v3>0?v3:1); dinv[base+3]=q; }
  if (blockIdx.x == 0 && threadIdx.x == 0) row[N] = E;
}

// ---------------- proj_fill: per-edge 12 projections (bf16), NO ATOMIC (epos from setup) ----
// record (32 B): words 0..5 = proj[0..11] as bf16 pairs (lh = l*4+h), word6 = src, word7 = dst
__global__ __launch_bounds__(256) void proj_fill(const int* __restrict__ ei, int E,
                                                 const int* __restrict__ row,
                                                 const int* __restrict__ epos,
                                                 const void* __restrict__ eattr,
                                                 const float* __restrict__ Mmat,
                                                 uint4* __restrict__ rec, int* __restrict__ perm,
                                                 const int* __restrict__ flag){
  __shared__ float sM[16][12];
  int tid = threadIdx.x;
  if (tid < 192) sM[tid/12][tid%12] = Mmat[tid];
  __syncthreads();
  int e = blockIdx.x*256 + tid;
  if (e >= E) return;
  int s = ei[e], d = ei[E + e];
  float v[16];
  if (flag[0]){
    const float4* pp = (const float4*)((const float*)eattr + (size_t)e*16);
    float4 a = pp[0], b = pp[1], c = pp[2], dd = pp[3];
    v[0]=a.x; v[1]=a.y; v[2]=a.z; v[3]=a.w;
    v[4]=b.x; v[5]=b.y; v[6]=b.z; v[7]=b.w;
    v[8]=c.x; v[9]=c.y; v[10]=c.z; v[11]=c.w;
    v[12]=dd.x; v[13]=dd.y; v[14]=dd.z; v[15]=dd.w;
  } else {
    const uint4* pp = (const uint4*)((const unsigned short*)eattr + (size_t)e*16);
    uint4 a = pp[0], b = pp[1];
    unsigned w[8] = {a.x,a.y,a.z,a.w,b.x,b.y,b.z,b.w};
    #pragma unroll
    for (int j = 0; j < 8; ++j){
      v[2*j]   = bf2f((unsigned short)(w[j] & 0xffffu));
      v[2*j+1] = bf2f((unsigned short)(w[j] >> 16));
    }
  }
  float p[12];
  #pragma unroll
  for (int j = 0; j < 12; ++j){
    float acc = 0.f;
    #pragma unroll
    for (int k = 0; k < 16; ++k) acc += v[k]*sM[k][j];
    p[j] = acc;
  }
  uint4 q0, q1;
  q0.x = (unsigned)f2bf(p[0])  | ((unsigned)f2bf(p[1])  << 16);
  q0.y = (unsigned)f2bf(p[2])  | ((unsigned)f2bf(p[3])  << 16);
  q0.z = (unsigned)f2bf(p[4])  | ((unsigned)f2bf(p[5])  << 16);
  q0.w = (unsigned)f2bf(p[6])  | ((unsigned)f2bf(p[7])  << 16);
  q1.x = (unsigned)f2bf(p[8])  | ((unsigned)f2bf(p[9])  << 16);
  q1.y = (unsigned)f2bf(p[10]) | ((unsigned)f2bf(p[11]) << 16);
  q1.z = (unsigned)s; q1.w = (unsigned)d;
  rec[(size_t)e*2]   = q0;   // coalesced, edge order
  rec[(size_t)e*2+1] = q1;
  perm[row[d] + epos[e]] = e;   // 4 B scattered store, no RMW
}

// ---------------- per-node mean of projected edge terms: 4 lanes/node ----------
__global__ __launch_bounds__(256) void mean_proj_k(const uint4* __restrict__ rec,
                                                   const int* __restrict__ perm,
                                                   const int* __restrict__ row,
                                                   const float2* __restrict__ dinv,
                                                   float* __restrict__ mp, int N){
  int idx = blockIdx.x*256 + threadIdx.x;
  int n = idx >> 2, q = idx & 3;
  if (n >= N) return;
  int r = row[n], deg = row[n+1] - r;
  float acc[12] = {};
  for (int e = q; e < deg; e += 4){
    int ed = perm[r + e];
    uint4 a = rec[(size_t)ed*2];
    uint2 b = *(const uint2*)(rec + (size_t)ed*2 + 1);
    unsigned w[6] = {a.x,a.y,a.z,a.w,b.x,b.y};
    #pragma unroll
    for (int j = 0; j < 6; ++j){
      acc[2*j]   += bf2f((unsigned short)(w[j] & 0xffffu));
      acc[2*j+1] += bf2f((unsigned short)(w[j] >> 16));
    }
  }
  #pragma unroll
  for (int m = 1; m < 4; m <<= 1){
    #pragma unroll
    for (int j = 0; j < 12; ++j) acc[j] += __shfl_xor(acc[j], m);
  }
  if (q == 0){
    float inv = dinv[n].x > 0.f ? dinv[n].y : 1.f;
    float* op = mp + (size_t)n*12;
    float4 o0, o1, o2;
    o0.x=acc[0]*inv; o0.y=acc[1]*inv; o0.z=acc[2]*inv; o0.w=acc[3]*inv;
    o1.x=acc[4]*inv; o1.y=acc[5]*inv; o1.z=acc[6]*inv; o1.w=acc[7]*inv;
    o2.x=acc[8]*inv; o2.y=acc[9]*inv; o2.z=acc[10]*inv; o2.w=acc[11]*inv;
    *(float4*)(op)   = o0;
    *(float4*)(op+4) = o1;
    *(float4*)(op+8) = o2;
  }
}

__device__ __forceinline__ float lrelu(float x){ return x > 0.f ? x : 0.2f*x; }
__device__ __forceinline__ float expg(float x){ return __expf(fminf(x, 0.f)); }

// shared EPI: attention scores + self-loop alpha, from acc[8] C-fragments
// mpL = mproj + layer*4 (stride 12 floats per node, MEANS; dinv.x = deg>0 indicator)
template<typename ACC>
__device__ __forceinline__ void att_epi(const ACC* acc, int m, int quad, int nodeBase, int N,
                                        const float* sAs, const float* sAd,
                                        const float* sCB,
                                        const float* __restrict__ mpL,
                                        const float2* __restrict__ dinv,
                                        float* __restrict__ a_src,
                                        float* __restrict__ a_dst,
                                        float* __restrict__ alpha_self)
{
  #pragma unroll
  for (int r2 = 0; r2 < 4; ++r2){
    float vs[4], vd[4];
    #pragma unroll
    for (int h = 0; h < 4; ++h){
      int c0 = (2*h)*16 + m, c1 = (2*h+1)*16 + m;
      vs[h] = acc[2*h][r2]*sAs[c0] + acc[2*h+1][r2]*sAs[c1];
      vd[h] = acc[2*h][r2]*sAd[c0] + acc[2*h+1][r2]*sAd[c1];
    }
    #pragma unroll
    for (int mm = 1; mm < 16; mm <<= 1){
      #pragma unroll
      for (int h = 0; h < 4; ++h){
        vs[h] += __shfl_xor(vs[h], mm);
        vd[h] += __shfl_xor(vd[h], mm);
      }
    }
    if (m == 0){
      int nd = nodeBase + quad*4 + r2;
      if (nd < N){
        float2 di = dinv[nd];
        float4 mp4 = *(const float4*)(mpL + (size_t)nd*12);
        float mpv[4] = {mp4.x, mp4.y, mp4.z, mp4.w};
        float aS[4];
        #pragma unroll
        for (int h = 0; h < 4; ++h)
          aS[h] = lrelu(vs[h] + vd[h] + sCB[h]*di.x + mpv[h]);
        float4 vsv, vdv, asv;
        vsv.x=vs[0]; vsv.y=vs[1]; vsv.z=vs[2]; vsv.w=vs[3];
        vdv.x=vd[0]; vdv.y=vd[1]; vdv.z=vd[2]; vdv.w=vd[3];
        asv.x=aS[0]; asv.y=aS[1]; asv.z=aS[2]; asv.w=aS[3];
        *(float4*)(a_src + (size_t)nd*4) = vsv;
        *(float4*)(a_dst + (size_t)nd*4) = vdv;
        *(float4*)(alpha_self + (size_t)nd*4) = asv;
      }
    }
  }
}

// ---------------- MFMA GEMM: out[N,128] = A[N,K](bf16) @ W[K,128] (+bias) ----------------
// OUTMODE: 0 = bf16 out (+EPI), 2 = dual fp32 + bf16 (no EPI)
template<int K, int OUTMODE, bool EPI>
__global__ __launch_bounds__(256) void mfma_lin(const unsigned short* __restrict__ A,
                                                const float* __restrict__ W,
                                                const float* __restrict__ bias,
                                                void* __restrict__ Out, void* __restrict__ Out2,
                                                int N,
                                                const float* __restrict__ attS,
                                                const float* __restrict__ attD,
                                                const float* __restrict__ cbl,
                                                const float* __restrict__ mpL,
                                                const float2* __restrict__ dinv,
                                                float* __restrict__ a_src,
                                                float* __restrict__ a_dst,
                                                float* __restrict__ alpha_self)
{
  constexpr int KP = K + 8;
  __shared__ unsigned short WT[128*KP];
  __shared__ float sAs[128], sAd[128];
  __shared__ float sCB[4];
  int tid = threadIdx.x;
  for (int i = tid; i < K*128; i += 256){
    int k = i >> 7, ch = i & 127;
    WT[ch*KP + k] = f2bf(W[i]);
  }
  if (EPI){
    if (tid < 128){ sAs[tid] = attS[tid]; sAd[tid] = attD[tid]; }
    if (tid < 4)  sCB[tid] = cbl[tid];
  }
  __syncthreads();
  int wid = tid >> 6, lane = tid & 63;
  int quad = lane >> 4, m = lane & 15;
  int nodeBase = blockIdx.x*64 + wid*16;
  int node = nodeBase + m;
  int nodeC = (node < N) ? node : 0;
  bf16x8 afr[K/32];
  #pragma unroll
  for (int kb = 0; kb < K/32; ++kb)
    afr[kb] = *(const bf16x8*)(A + (size_t)nodeC*K + kb*32 + quad*8);
  f32x4 acc[8] = {};
  #pragma unroll
  for (int t = 0; t < 8; ++t){
    #pragma unroll
    for (int kb = 0; kb < K/32; ++kb){
      bf16x8 bfr = *(const bf16x8*)&WT[(t*16 + m)*KP + kb*32 + quad*8];
      acc[t] = __builtin_amdgcn_mfma_f32_16x16x32_bf16(afr[kb], bfr, acc[t], 0, 0, 0);
    }
  }
  #pragma unroll
  for (int t = 0; t < 8; ++t){
    int ch = t*16 + m;
    float bv = bias ? bias[ch] : 0.f;
    #pragma unroll
    for (int r2 = 0; r2 < 4; ++r2){
      int nd = nodeBase + quad*4 + r2;
      if (nd < N){
        float v = acc[t][r2] + bv;
        if (OUTMODE == 0){
          ((unsigned short*)Out)[(size_t)nd*HID + ch] = f2bf(v);
        } else {
          ((float*)Out)[(size_t)nd*HID + ch] = v;
          ((unsigned short*)Out2)[(size_t)nd*HID + ch] = f2bf(v);
        }
      }
    }
  }
  if (EPI)
    att_epi(acc, m, quad, nodeBase, N, sAs, sAd, sCB,
            mpL, dinv, a_src, a_dst, alpha_self);
}

// ---------------- fused BN + ReLU + residual + GEMM (+EPI / external out) -------------
// hg is bf16 (GAT output). OUTMODE 0: bf16 xh out + EPI + fp32 h out; 1: external out
// bnsum/bnsq are 64-way BANKED: [64][128]; prologue reduces the banks.
template<int OUTMODE, bool WRITEH>
__global__ __launch_bounds__(256) void bn_mfma(const unsigned short* __restrict__ hg,
                                               const float* __restrict__ hprev,
                                               const float* __restrict__ bnsum,
                                               const float* __restrict__ bnsq,
                                               const float* __restrict__ gamma,
                                               const float* __restrict__ beta,
                                               const float* __restrict__ W,
                                               const float* __restrict__ bias,
                                               void* __restrict__ Out,
                                               float* __restrict__ hout,
                                               int N, const int* __restrict__ flag,
                                               const float* __restrict__ attS,
                                               const float* __restrict__ attD,
                                               const float* __restrict__ cbl,
                                               const float* __restrict__ mpL,
                                               const float2* __restrict__ dinv,
                                               float* __restrict__ a_src,
                                               float* __restrict__ a_dst,
                                               float* __restrict__ alpha_self)
{
  constexpr int K = 128, KP = 136;
  __shared__ unsigned short WT[128*KP];
  __shared__ float sSc[128], sSh[128];
  __shared__ float sAs[128], sAd[128];
  __shared__ float sCB[4];
  int tid = threadIdx.x;
  for (int i = tid; i < K*128; i += 256){
    int k = i >> 7, ch = i & 127;
    WT[ch*KP + k] = f2bf(W[i]);
  }
  if (tid < 128){
    float s = 0.f, q = 0.f;
    #pragma unroll 8
    for (int b = 0; b < 64; ++b){
      s += bnsum[b*128 + tid];
      q += bnsq[b*128 + tid];
    }
    float mean = s / (float)N;
    float var  = fmaxf(q / (float)N - mean*mean, 0.f);
    float sc = gamma[tid] * rsqrtf(var + 1e-5f);
    sSc[tid] = sc;
    sSh[tid] = beta[tid] - mean*sc;
    if (OUTMODE == 0){ sAs[tid] = attS[tid]; sAd[tid] = attD[tid]; }
  }
  if (OUTMODE == 0){
    if (tid < 4)  sCB[tid] = cbl[tid];
  }
  __syncthreads();
  int wid = tid >> 6, lane = tid & 63;
  int quad = lane >> 4, m = lane & 15;
  int nodeBase = blockIdx.x*64 + wid*16;
  int node = nodeBase + m;
  int nodeC = (node < N) ? node : 0;
  bf16x8 afr[4];
  #pragma unroll
  for (int kb = 0; kb < 4; ++kb){
    int cbase = kb*32 + quad*8;
    uint4 gu = *(const uint4*)(hg + (size_t)nodeC*K + cbase);
    const float4* pp = (const float4*)(hprev + (size_t)nodeC*K + cbase);
    float4 p0 = pp[0], p1 = pp[1];
    unsigned gw[4] = {gu.x, gu.y, gu.z, gu.w};
    float pv[8] = {p0.x,p0.y,p0.z,p0.w,p1.x,p1.y,p1.z,p1.w};
    float r[8];
    #pragma unroll
    for (int j = 0; j < 8; ++j){
      float g = bf2f((unsigned short)((j & 1) ? (gw[j>>1] >> 16) : (gw[j>>1] & 0xffffu)));
      float t = g*sSc[cbase+j] + sSh[cbase+j];
      t = t > 0.f ? t : 0.f;
      r[j] = t + pv[j];
    }
    if (WRITEH && node < N){
      float4 o0, o1;
      o0.x=r[0]; o0.y=r[1]; o0.z=r[2]; o0.w=r[3];
      o1.x=r[4]; o1.y=r[5]; o1.z=r[6]; o1.w=r[7];
      float4* hp = (float4*)(hout + (size_t)node*K + cbase);
      hp[0] = o0; hp[1] = o1;
    }
    bf16x8 f;
    #pragma unroll
    for (int j = 0; j < 8; ++j) f[j] = (short)f2bf(r[j]);
    afr[kb] = f;
  }
  f32x4 acc[8] = {};
  #pragma unroll
  for (int t = 0; t < 8; ++t){
    #pragma unroll
    for (int kb = 0; kb < 4; ++kb){
      bf16x8 bfr = *(const bf16x8*)&WT[(t*16 + m)*KP + kb*32 + quad*8];
      acc[t] = __builtin_amdgcn_mfma_f32_16x16x32_bf16(afr[kb], bfr, acc[t], 0, 0, 0);
    }
  }
  bool f32out = (OUTMODE == 1) && (flag[0] != 0);
  #pragma unroll
  for (int t = 0; t < 8; ++t){
    int ch = t*16 + m;
    float bv = bias ? bias[ch] : 0.f;
    #pragma unroll
    for (int r2 = 0; r2 < 4; ++r2){
      int nd = nodeBase + quad*4 + r2;
      if (nd < N){
        float v = acc[t][r2] + bv;
        if (OUTMODE == 0) ((unsigned short*)Out)[(size_t)nd*HID + ch] = f2bf(v);
        else if (f32out)  ((float*)Out)[(size_t)nd*HID + ch] = v;
        else              ((unsigned short*)Out)[(size_t)nd*HID + ch] = f2bf(v);
      }
    }
  }
  if (OUTMODE == 0)
    att_epi(acc, m, quad, nodeBase, N, sAs, sAd, sCB,
            mpL, dinv, a_src, a_dst, alpha_self);
}

// ---- inline per-edge alpha: perm -> record gather -> lrelu(as + ad + proj[layer]) ----
__device__ __forceinline__ float4 edge_alpha4(const unsigned* __restrict__ recw,
                                              const int* __restrict__ perm, int pos,
                                              const float* __restrict__ a_src,
                                              float4 adn, int layer, int* src_out){
  int e0 = perm[pos];
  const unsigned* rp = recw + (size_t)e0*8;
  unsigned w0 = rp[2*layer], w1 = rp[2*layer+1];
  int s = (int)rp[6];
  float4 as4 = *(const float4*)(a_src + (size_t)s*4);
  float4 o;
  o.x = lrelu(as4.x + adn.x + bf2f((unsigned short)(w0 & 0xffffu)));
  o.y = lrelu(as4.y + adn.y + bf2f((unsigned short)(w0 >> 16)));
  o.z = lrelu(as4.z + adn.z + bf2f((unsigned short)(w1 & 0xffffu)));
  o.w = lrelu(as4.w + adn.w + bf2f((unsigned short)(w1 >> 16)));
  *src_out = s;
  return o;
}

__device__ __forceinline__ void acc2(unsigned u, float q, float& a0, float& a1){
  union { unsigned i; float f; } lo, hi;
  lo.i = u << 16; hi.i = u & 0xffff0000u;
  a0 += q*lo.f; a1 += q*hi.f;
}

// ---------------- GAT aggregation: 32 lanes/node (2 nodes/wave), fused BN stats ----
__global__ __launch_bounds__(256) void gat_agg(
    const unsigned short* __restrict__ xh,
    const uint4* __restrict__ rec, const int* __restrict__ perm,
    const int* __restrict__ row,
    const float* __restrict__ a_src, const float* __restrict__ a_dst,
    const float4* __restrict__ alpha_self,
    const float* __restrict__ bconv, unsigned short* __restrict__ hout,
    float* __restrict__ bnsumB, float* __restrict__ bnsqB,
    int N, int layer)
{
  __shared__ float sPf[8][256];      // [node][e*4+h]
  __shared__ int   sOff[8][64];
  __shared__ float sBS[8][128];      // per-node channel sums
  __shared__ float sBQ[8][128];      // per-node channel squares
  int tid = threadIdx.x;
  int wid = tid >> 6, lane = tid & 63;
  int half = lane >> 5, sl = lane & 31;
  int g = wid*2 + half;
  int n = blockIdx.x*8 + g;
  int nn = (n < N) ? n : 0;
  int r = row[nn];
  int deg = row[nn+1] - r;
  if (n >= N) deg = 0;
  const unsigned* recw = (const unsigned*)rec;

  float4 adn = *(const float4*)(a_dst + (size_t)nn*4);
  float4 aA; aA.x = aA.y = aA.z = aA.w = -1e30f;
  float4 aB; aB.x = aB.y = aB.z = aB.w = -1e30f;
  int sA = 0, sB = 0;
  if (sl < deg)      aA = edge_alpha4(recw, perm, r + sl,      a_src, adn, layer, &sA);
  if (32 + sl < deg) aB = edge_alpha4(recw, perm, r + 32 + sl, a_src, adn, layer, &sB);
  float mx0 = fmaxf(aA.x, aB.x), mx1 = fmaxf(aA.y, aB.y);
  float mx2 = fmaxf(aA.z, aB.z), mx3 = fmaxf(aA.w, aB.w);
  for (int e = 64 + sl; e < deg; e += 32){   // rare (deg>64)
    int st;
    float4 a4 = edge_alpha4(recw, perm, r + e, a_src, adn, layer, &st);
    mx0 = fmaxf(mx0, a4.x); mx1 = fmaxf(mx1, a4.y);
    mx2 = fmaxf(mx2, a4.z); mx3 = fmaxf(mx3, a4.w);
  }
  #pragma unroll
  for (int m = 1; m < 32; m <<= 1){
    mx0 = fmaxf(mx0, __shfl_xor(mx0,m)); mx1 = fmaxf(mx1, __shfl_xor(mx1,m));
    mx2 = fmaxf(mx2, __shfl_xor(mx2,m)); mx3 = fmaxf(mx3, __shfl_xor(mx3,m));
  }
  float4 sf = alpha_self[nn];
  mx0 = fmaxf(mx0, sf.x); mx1 = fmaxf(mx1, sf.y);
  mx2 = fmaxf(mx2, sf.z); mx3 = fmaxf(mx3, sf.w);

  float d0 = 0.f, d1 = 0.f, d2 = 0.f, d3 = 0.f;
  if (sl < deg){
    float4 p;
    p.x = expg(aA.x-mx0); p.y = expg(aA.y-mx1);
    p.z = expg(aA.z-mx2); p.w = expg(aA.w-mx3);
    *(float4*)&sPf[g][sl*4] = p;
    sOff[g][sl] = sA << 8;
    d0 = p.x; d1 = p.y; d2 = p.z; d3 = p.w;
  }
  if (32 + sl < deg){
    float4 p;
    p.x = expg(aB.x-mx0); p.y = expg(aB.y-mx1);
    p.z = expg(aB.z-mx2); p.w = expg(aB.w-mx3);
    *(float4*)&sPf[g][(32+sl)*4] = p;
    sOff[g][32+sl] = sB << 8;
    d0 += p.x; d1 += p.y; d2 += p.z; d3 += p.w;
  }
  for (int e = 64 + sl; e < deg; e += 32){   // rare
    int st;
    float4 a4 = edge_alpha4(recw, perm, r + e, a_src, adn, layer, &st);
    d0 += expg(a4.x-mx0); d1 += expg(a4.y-mx1);
    d2 += expg(a4.z-mx2); d3 += expg(a4.w-mx3);
  }
  #pragma unroll
  for (int m = 1; m < 32; m <<= 1){
    d0 += __shfl_xor(d0,m); d1 += __shfl_xor(d1,m); d2 += __shfl_xor(d2,m); d3 += __shfl_xor(d3,m);
  }
  float ps0 = expg(sf.x-mx0), ps1 = expg(sf.y-mx1), ps2 = expg(sf.z-mx2), ps3 = expg(sf.w-mx3);
  float i0 = 1.0f/(d0+ps0+1e-16f), i1 = 1.0f/(d1+ps1+1e-16f);
  float i2 = 1.0f/(d2+ps2+1e-16f), i3 = 1.0f/(d3+ps3+1e-16f);

  // gather: lane covers channels sl*4 .. sl*4+3; head h = sl>>3
  int h = sl >> 3;
  float mxh = h==0 ? mx0 : h==1 ? mx1 : h==2 ? mx2 : mx3;
  float ih  = h==0 ? i0  : h==1 ? i1  : h==2 ? i2  : i3;
  float psh = h==0 ? ps0 : h==1 ? ps1 : h==2 ? ps2 : ps3;
  const char* xb = (const char*)xh;
  float a0=0.f, a1=0.f, a2=0.f, a3=0.f;
  int dmin = deg < 64 ? deg : 64;
  int e = 0;
  for (; e + 4 <= dmin; e += 4){
    int oA = sOff[g][e+0], oB = sOff[g][e+1], oC = sOff[g][e+2], oD = sOff[g][e+3];
    float qA = sPf[g][(e+0)*4 + h], qB = sPf[g][(e+1)*4 + h];
    float qC = sPf[g][(e+2)*4 + h], qD = sPf[g][(e+3)*4 + h];
    uint2 xA = *(const uint2*)(xb + (size_t)oA + sl*8);
    uint2 xB = *(const uint2*)(xb + (size_t)oB + sl*8);
    uint2 xC = *(const uint2*)(xb + (size_t)oC + sl*8);
    uint2 xD = *(const uint2*)(xb + (size_t)oD + sl*8);
    acc2(xA.x, qA, a0,a1); acc2(xA.y, qA, a2,a3);
    acc2(xB.x, qB, a0,a1); acc2(xB.y, qB, a2,a3);
    acc2(xC.x, qC, a0,a1); acc2(xC.y, qC, a2,a3);
    acc2(xD.x, qD, a0,a1); acc2(xD.y, qD, a2,a3);
  }
  for (; e < dmin; ++e){
    int o = sOff[g][e];
    float q = sPf[g][e*4 + h];
    uint2 xv = *(const uint2*)(xb + (size_t)o + sl*8);
    acc2(xv.x, q, a0,a1); acc2(xv.y, q, a2,a3);
  }
  for (; e < deg; ++e){            // rare (deg>64): recompute alpha
    int st;
    float4 a4 = edge_alpha4(recw, perm, r + e, a_src, adn, layer, &st);
    float av = h==0 ? a4.x : h==1 ? a4.y : h==2 ? a4.z : a4.w;
    float q = expg(av - mxh);
    uint2 xv = *(const uint2*)(xb + (size_t)st*256 + sl*8);
    acc2(xv.x, q, a0,a1); acc2(xv.y, q, a2,a3);
  }
  float fo0=0.f, fo1=0.f, fo2=0.f, fo3=0.f;
  if (n < N){
    uint2 xn = *(const uint2*)(xb + (size_t)nn*256 + sl*8);
    acc2(xn.x, psh, a0,a1); acc2(xn.y, psh, a2,a3);
    float4 bc = *(const float4*)(bconv + layer*128 + sl*4);
    fo0 = a0*ih + bc.x; fo1 = a1*ih + bc.y;
    fo2 = a2*ih + bc.z; fo3 = a3*ih + bc.w;
    uint2 ov;
    ov.x = (unsigned)f2bf(fo0) | ((unsigned)f2bf(fo1) << 16);
    ov.y = (unsigned)f2bf(fo2) | ((unsigned)f2bf(fo3) << 16);
    *(uint2*)((char*)hout + (size_t)nn*256 + sl*8) = ov;
  }
  // fused BN stats: per-node channel partials in LDS, then banked atomics
  float4 vS; vS.x=fo0; vS.y=fo1; vS.z=fo2; vS.w=fo3;
  float4 vQ; vQ.x=fo0*fo0; vQ.y=fo1*fo1; vQ.z=fo2*fo2; vQ.w=fo3*fo3;
  *(float4*)&sBS[g][sl*4] = vS;
  *(float4*)&sBQ[g][sl*4] = vQ;
  __syncthreads();
  if (tid < 128){
    float ss = 0.f, qq = 0.f;
    #pragma unroll
    for (int k = 0; k < 8; ++k){ ss += sBS[k][tid]; qq += sBQ[k][tid]; }
    int bank = (blockIdx.x & 63) << 7;   // *128
    atomicAdd(&bnsumB[bank + tid], ss);
    atomicAdd(&bnsqB[bank + tid], qq);
  }
}

// ---------------- host ----------------
extern "C" void kernel_launch(void* const* d_in, const int* in_sizes, int n_in,
                              void* d_out, int out_size, void* d_ws, size_t ws_size,
                              hipStream_t stream)
{
  const void* x        = d_in[0];
  const int*  ei       = (const int*)d_in[1];
  const void* eattr    = d_in[2];
  int N = in_sizes[0] / 64;
  int E = in_sizes[1] / 2;

  char* p = (char*)d_ws;
  auto alloc = [&](size_t bytes)->char* {
    char* r = p; p += (bytes + 255) & ~(size_t)255; return r;
  };
  // zero-region first (one memset)
  int*   deg    = (int*)alloc((size_t)N*4);
  float* bnsumB = (float*)alloc(3*64*128*4);   // banked BN partials
  float* bnsqB  = (float*)alloc(3*64*128*4);
  size_t zbytes = (size_t)(p - (char*)deg);
  int*   dflag  = (int*)alloc(256);
  int*   row    = (int*)alloc(((size_t)N + 1)*4);
  int*   part   = (int*)alloc(1024*4);
  int*   epos   = (int*)alloc((size_t)E*4);
  uint4* rec    = (uint4*)alloc((size_t)E*32);
  int*   perm   = (int*)alloc((size_t)E*4);
  float* hA     = (float*)alloc((size_t)N*128*4);
  float* hB     = (float*)alloc((size_t)N*128*4);
  unsigned short* hGb = (unsigned short*)alloc((size_t)N*128*2);
  unsigned short* hAb = (unsigned short*)alloc((size_t)N*128*2);
  unsigned short* xhb = (unsigned short*)alloc((size_t)N*128*2);
  float* a_src  = (float*)alloc((size_t)N*4*4);
  float* a_dst  = (float*)alloc((size_t)N*4*4);
  float* alphaS = (float*)alloc((size_t)N*4*4);
  float* mproj  = (float*)alloc((size_t)N*12*4);
  float2* dinv  = (float2*)alloc((size_t)N*8);
  float* Mmat   = (float*)alloc(16*12*4);
  float* cbias  = (float*)alloc(12*4);
  unsigned short* xc  = (unsigned short*)alloc((size_t)N*64*2);
  float* wc     = (float*)alloc(130000*4);

  // canonical weight buffers (fp32)
  int   woff[14] = {0, 8192, 8320, 10368, 10496, 59648, 108800, 109184,
                    109568, 109952, 110336, 110720, 111104, 127488};
  int   wcnt[14] = {8192, 128, 2048, 128, 49152, 49152, 384, 384, 384, 384, 384, 384, 16384, 128};
  CvList L; L.n = 14;
  for (int a = 0; a < 14; ++a){ L.src[a] = d_in[3+a]; L.dst[a] = wc + woff[a]; L.cnt[a] = wcnt[a]; }
  float* cW_atom = wc + woff[0];  float* cb_atom = wc + woff[1];
  float* cW_bond = wc + woff[2];  float* cb_bond = wc + woff[3];
  float* cW_lin  = wc + woff[4];  float* cW_edge = wc + woff[5];
  float* catt_s  = wc + woff[6];  float* catt_d  = wc + woff[7];
  float* catt_e  = wc + woff[8];  float* cbconv  = wc + woff[9];
  float* cgamma  = wc + woff[10]; float* cbeta   = wc + woff[11];
  float* cW_out  = wc + woff[12]; float* cb_out  = wc + woff[13];

  hipMemsetAsync(deg, 0, zbytes, stream);
  setup<<<(E + 255)/256, 256, 0, stream>>>(L, x, xc, N*16, dflag, ei, E, deg, epos);
  precompute_M<<<1, 256, 0, stream>>>(cW_edge, catt_e, cW_bond, cb_bond, Mmat, cbias);
  int P = (N + 1023)/1024;
  scan_part<<<P, 256, 0, stream>>>(deg, part, N);
  scan_top<<<1, 64, 0, stream>>>(part, P);
  scan_write<<<P, 256, 0, stream>>>(deg, part, row, dinv, N, E);
  proj_fill<<<(E + 255)/256, 256, 0, stream>>>(ei, E, row, epos, eattr, Mmat, rec, perm, dflag);
  mean_proj_k<<<((size_t)N*4 + 255)/256, 256, 0, stream>>>(rec, perm, row, dinv, mproj, N);

  // atom embedding: hA(fp32) + hAb(bf16) = x @ W_atom + b_atom
  mfma_lin<64, 2, false><<<(N + 63)/64, 256, 0, stream>>>(xc, cW_atom, cb_atom, hA, hAb, N,
      nullptr, nullptr, nullptr, nullptr, nullptr, nullptr, nullptr, nullptr);
  // layer-0 GEMM + attention scores + self-loop alpha
  mfma_lin<128, 0, true><<<(N + 63)/64, 256, 0, stream>>>(hAb, cW_lin, nullptr, xhb, nullptr, N,
      catt_s, catt_d, cbias, mproj, dinv, a_src, a_dst, alphaS);

  float* cur = hA; float* oth = hB;
  for (int l = 0; l < 3; ++l){
    gat_agg<<<(N + 7)/8, 256, 0, stream>>>(xhb, rec, perm, row, a_src, a_dst,
                                           (const float4*)alphaS, cbconv, hGb,
                                           bnsumB + l*8192, bnsqB + l*8192, N, l);
    if (l < 2){
      bn_mfma<0, true><<<(N + 63)/64, 256, 0, stream>>>(hGb, cur,
          bnsumB + l*8192, bnsqB + l*8192, cgamma + l*128, cbeta + l*128,
          cW_lin + (size_t)(l+1)*16384, nullptr, xhb, oth, N, dflag,
          catt_s + (l+1)*128, catt_d + (l+1)*128, cbias + (l+1)*4,
          mproj + (l+1)*4, dinv, a_src, a_dst, alphaS);
      float* t = cur; cur = oth; oth = t;
    } else {
      bn_mfma<1, false><<<(N + 63)/64, 256, 0, stream>>>(hGb, cur,
          bnsumB + l*8192, bnsqB + l*8192, cgamma + l*128, cbeta + l*128,
          cW_out, cb_out, d_out, nullptr, N, dflag,
          nullptr, nullptr, nullptr, nullptr, nullptr, nullptr, nullptr, nullptr);
    }
  }
}

// Round 12
// 440.860 us; speedup vs baseline: 1.0722x; 1.0041x over previous
//
#include <hip/hip_runtime.h>
#include <stdint.h>

#define HID 128

typedef __attribute__((ext_vector_type(8))) short bf16x8;
typedef __attribute__((ext_vector_type(4))) float f32x4;

__device__ __forceinline__ float bf2f(unsigned short u){
  union { unsigned int i; float f; } x; x.i = ((unsigned int)u) << 16; return x.f;
}
__device__ __forceinline__ unsigned short f2bf(float f){
  union { float f; unsigned int i; } x; x.f = f;
  unsigned int b = x.i;
  return (unsigned short)((b + 0x7fffu + ((b >> 16) & 1u)) >> 16);
}

// ---------------- setup: dtype flag + weight conv + x->bf16 + deg_count + edge pos ----
struct CvList {
  const void* src[16];
  float* dst[16];
  int cnt[16];
  int n;
};
__global__ __launch_bounds__(256) void setup(CvList L, const void* x,
                                             unsigned short* xc, int n4,
                                             int* __restrict__ dflag,
                                             const int* __restrict__ ei, int E,
                                             int* __restrict__ deg,
                                             int* __restrict__ epos){
  __shared__ int red[4];
  int tid = threadIdx.x;
  const unsigned short* xs = (const unsigned short*)x;
  unsigned short u = xs[tid];
  int ex = (u >> 7) & 0xFF;
  int v = ((((tid & 1) == 0) && u == 0) ? 1 : 0) | ((ex >= 140) ? 65536 : 0);
  #pragma unroll
  for (int m = 1; m < 64; m <<= 1) v += __shfl_xor(v, m);
  if ((tid & 63) == 0) red[tid >> 6] = v;
  __syncthreads();
  int tot = red[0] + red[1] + red[2] + red[3];
  bool isf32 = ((tot & 0xffff) >= 32) || ((tot >> 16) >= 8);
  if (blockIdx.x == 0 && tid == 0) dflag[0] = isf32 ? 1 : 0;
  // degree count + slot capture (whole grid)
  int e = blockIdx.x*256 + tid;
  if (e < E) epos[e] = atomicAdd(&deg[ei[E + e]], 1);
  // weights + x conversion (whole grid)
  int gstride = gridDim.x*256;
  int gid = blockIdx.x*256 + tid;
  for (int a = 0; a < L.n; ++a){
    const void* s = L.src[a];
    float* d = L.dst[a];
    int c = L.cnt[a];
    for (int i = gid; i < c; i += gstride)
      d[i] = isf32 ? ((const float*)s)[i] : bf2f(((const unsigned short*)s)[i]);
  }
  for (int i = gid; i < n4; i += gstride){
    if (isf32){
      float4 q = ((const float4*)x)[i];
      ushort4 o; o.x = f2bf(q.x); o.y = f2bf(q.y); o.z = f2bf(q.z); o.w = f2bf(q.w);
      ((ushort4*)xc)[i] = o;
    } else {
      ((ushort4*)xc)[i] = ((const ushort4*)x)[i];
    }
  }
}

// ---------------- scan_part + fused precompute_M (extra block P) ----------------
// blocks [0,P): per-1024-chunk degree sums -> part[b] (raw, NOT scanned)
// block P: M = W_bond @ (W_edge @ att_edge), cbias = b_bond @ ve
__global__ __launch_bounds__(256) void scan_part_pm(
    const int* __restrict__ deg, int* __restrict__ part, int N, int P,
    const float* __restrict__ We, const float* __restrict__ ae,
    const float* __restrict__ Wb, const float* __restrict__ bb,
    float* __restrict__ Mout, float* __restrict__ cb)
{
  __shared__ float smem[128*12];   // union: ve (6 KB) | sh (1 KB)
  int tid = threadIdx.x;
  if ((int)blockIdx.x < P){
    int* sh = (int*)smem;
    int base = blockIdx.x*1024;
    int s = 0;
    for (int i = tid; i < 1024; i += 256){ int j = base + i; if (j < N) s += deg[j]; }
    sh[tid] = s; __syncthreads();
    for (int m = 128; m > 0; m >>= 1){ if (tid < m) sh[tid] += sh[tid + m]; __syncthreads(); }
    if (tid == 0) part[blockIdx.x] = sh[0];
  } else {
    float* ve = smem;
    for (int i = tid; i < 128*12; i += 256){
      int c = i / 12, lh = i % 12; int l = lh >> 2, h = lh & 3;
      float s = 0.f;
      for (int d = 0; d < 32; ++d)
        s += We[l*16384 + c*128 + h*32 + d] * ae[l*128 + h*32 + d];
      ve[i] = s;
    }
    __syncthreads();
    for (int i = tid; i < 16*12; i += 256){
      int k = i / 12, lh = i % 12;
      float s = 0.f;
      for (int c = 0; c < 128; ++c) s += Wb[k*128 + c] * ve[c*12 + lh];
      Mout[i] = s;
    }
    for (int i = tid; i < 12; i += 256){
      float s = 0.f;
      for (int c = 0; c < 128; ++c) s += bb[c] * ve[c*12 + i];
      cb[i] = s;
    }
  }
}

// ---------------- scan_write: self top-scan (part[] holds RAW chunk sums) -------
// also emits dinv[n] = {deg>0 ? 1 : 0, 1/max(deg,1)}
__global__ __launch_bounds__(256) void scan_write(const int* __restrict__ deg, const int* __restrict__ part,
                                                  int* __restrict__ row, float2* __restrict__ dinv,
                                                  int N, int E){
  __shared__ int sh[256];
  int tid = threadIdx.x;
  // block prefix = sum of part[i] for i < blockIdx.x (P<=1024, typically ~49)
  int pb = 0;
  for (int i = tid; i < (int)blockIdx.x; i += 256) pb += part[i];
  sh[tid] = pb; __syncthreads();
  for (int m = 128; m > 0; m >>= 1){ if (tid < m) sh[tid] += sh[tid + m]; __syncthreads(); }
  int blockBase = sh[0];
  __syncthreads();

  int base = blockIdx.x*1024 + tid*4;
  int v0=0,v1=0,v2=0,v3=0;
  if (base+0 < N) v0 = deg[base+0];
  if (base+1 < N) v1 = deg[base+1];
  if (base+2 < N) v2 = deg[base+2];
  if (base+3 < N) v3 = deg[base+3];
  int s = v0+v1+v2+v3;
  sh[tid] = s; __syncthreads();
  for (int m = 1; m < 256; m <<= 1){
    int t = (tid >= m) ? sh[tid - m] : 0;
    __syncthreads();
    sh[tid] += t;
    __syncthreads();
  }
  int excl = sh[tid] - s + blockBase;
  if (base+0 < N){ row[base+0] = excl; float2 q; q.x = v0>0?1.f:0.f; q.y = 1.f/(float)(v0>0?v0:1); dinv[base+0]=q; } excl += v0;
  if (base+1 < N){ row[base+1] = excl; float2 q; q.x = v1>0?1.f:0.f; q.y = 1.f/(float)(v1>0?v1:1); dinv[base+1]=q; } excl += v1;
  if (base+2 < N){ row[base+2] = excl; float2 q; q.x = v2>0?1.f:0.f; q.y = 1.f/(float)(v2>0?v2:1); dinv[base+2]=q; } excl += v2;
  if (base+3 < N){ row[base+3] = excl; float2 q; q.x = v3>0?1.f:0.f; q.y = 1.f/(float)(v3>0?v3:1); dinv[base+3]=q; }
  if (blockIdx.x == 0 && tid == 0) row[N] = E;
}

// ---------------- proj_fill: per-edge 12 projections (bf16), NO ATOMIC (epos from setup) ----
__global__ __launch_bounds__(256) void proj_fill(const int* __restrict__ ei, int E,
                                                 const int* __restrict__ row,
                                                 const int* __restrict__ epos,
                                                 const void* __restrict__ eattr,
                                                 const float* __restrict__ Mmat,
                                                 uint4* __restrict__ rec, int* __restrict__ perm,
                                                 const int* __restrict__ flag){
  __shared__ float sM[16][12];
  int tid = threadIdx.x;
  if (tid < 192) sM[tid/12][tid%12] = Mmat[tid];
  __syncthreads();
  int e = blockIdx.x*256 + tid;
  if (e >= E) return;
  int s = ei[e], d = ei[E + e];
  float v[16];
  if (flag[0]){
    const float4* pp = (const float4*)((const float*)eattr + (size_t)e*16);
    float4 a = pp[0], b = pp[1], c = pp[2], dd = pp[3];
    v[0]=a.x; v[1]=a.y; v[2]=a.z; v[3]=a.w;
    v[4]=b.x; v[5]=b.y; v[6]=b.z; v[7]=b.w;
    v[8]=c.x; v[9]=c.y; v[10]=c.z; v[11]=c.w;
    v[12]=dd.x; v[13]=dd.y; v[14]=dd.z; v[15]=dd.w;
  } else {
    const uint4* pp = (const uint4*)((const unsigned short*)eattr + (size_t)e*16);
    uint4 a = pp[0], b = pp[1];
    unsigned w[8] = {a.x,a.y,a.z,a.w,b.x,b.y,b.z,b.w};
    #pragma unroll
    for (int j = 0; j < 8; ++j){
      v[2*j]   = bf2f((unsigned short)(w[j] & 0xffffu));
      v[2*j+1] = bf2f((unsigned short)(w[j] >> 16));
    }
  }
  float p[12];
  #pragma unroll
  for (int j = 0; j < 12; ++j){
    float acc = 0.f;
    #pragma unroll
    for (int k = 0; k < 16; ++k) acc += v[k]*sM[k][j];
    p[j] = acc;
  }
  uint4 q0, q1;
  q0.x = (unsigned)f2bf(p[0])  | ((unsigned)f2bf(p[1])  << 16);
  q0.y = (unsigned)f2bf(p[2])  | ((unsigned)f2bf(p[3])  << 16);
  q0.z = (unsigned)f2bf(p[4])  | ((unsigned)f2bf(p[5])  << 16);
  q0.w = (unsigned)f2bf(p[6])  | ((unsigned)f2bf(p[7])  << 16);
  q1.x = (unsigned)f2bf(p[8])  | ((unsigned)f2bf(p[9])  << 16);
  q1.y = (unsigned)f2bf(p[10]) | ((unsigned)f2bf(p[11]) << 16);
  q1.z = (unsigned)s; q1.w = (unsigned)d;
  rec[(size_t)e*2]   = q0;   // coalesced, edge order
  rec[(size_t)e*2+1] = q1;
  perm[row[d] + epos[e]] = e;   // 4 B scattered store, no RMW
}

// ---------------- per-node mean of projected edge terms: 4 lanes/node ----------
__global__ __launch_bounds__(256) void mean_proj_k(const uint4* __restrict__ rec,
                                                   const int* __restrict__ perm,
                                                   const int* __restrict__ row,
                                                   const float2* __restrict__ dinv,
                                                   float* __restrict__ mp, int N){
  int idx = blockIdx.x*256 + threadIdx.x;
  int n = idx >> 2, q = idx & 3;
  if (n >= N) return;
  int r = row[n], deg = row[n+1] - r;
  float acc[12] = {};
  for (int e = q; e < deg; e += 4){
    int ed = perm[r + e];
    uint4 a = rec[(size_t)ed*2];
    uint2 b = *(const uint2*)(rec + (size_t)ed*2 + 1);
    unsigned w[6] = {a.x,a.y,a.z,a.w,b.x,b.y};
    #pragma unroll
    for (int j = 0; j < 6; ++j){
      acc[2*j]   += bf2f((unsigned short)(w[j] & 0xffffu));
      acc[2*j+1] += bf2f((unsigned short)(w[j] >> 16));
    }
  }
  #pragma unroll
  for (int m = 1; m < 4; m <<= 1){
    #pragma unroll
    for (int j = 0; j < 12; ++j) acc[j] += __shfl_xor(acc[j], m);
  }
  if (q == 0){
    float inv = dinv[n].x > 0.f ? dinv[n].y : 1.f;
    float* op = mp + (size_t)n*12;
    float4 o0, o1, o2;
    o0.x=acc[0]*inv; o0.y=acc[1]*inv; o0.z=acc[2]*inv; o0.w=acc[3]*inv;
    o1.x=acc[4]*inv; o1.y=acc[5]*inv; o1.z=acc[6]*inv; o1.w=acc[7]*inv;
    o2.x=acc[8]*inv; o2.y=acc[9]*inv; o2.z=acc[10]*inv; o2.w=acc[11]*inv;
    *(float4*)(op)   = o0;
    *(float4*)(op+4) = o1;
    *(float4*)(op+8) = o2;
  }
}

__device__ __forceinline__ float lrelu(float x){ return x > 0.f ? x : 0.2f*x; }
__device__ __forceinline__ float expg(float x){ return __expf(fminf(x, 0.f)); }

// shared EPI: attention scores + self-loop alpha, from acc[8] C-fragments
template<typename ACC>
__device__ __forceinline__ void att_epi(const ACC* acc, int m, int quad, int nodeBase, int N,
                                        const float* sAs, const float* sAd,
                                        const float* sCB,
                                        const float* __restrict__ mpL,
                                        const float2* __restrict__ dinv,
                                        float* __restrict__ a_src,
                                        float* __restrict__ a_dst,
                                        float* __restrict__ alpha_self)
{
  #pragma unroll
  for (int r2 = 0; r2 < 4; ++r2){
    float vs[4], vd[4];
    #pragma unroll
    for (int h = 0; h < 4; ++h){
      int c0 = (2*h)*16 + m, c1 = (2*h+1)*16 + m;
      vs[h] = acc[2*h][r2]*sAs[c0] + acc[2*h+1][r2]*sAs[c1];
      vd[h] = acc[2*h][r2]*sAd[c0] + acc[2*h+1][r2]*sAd[c1];
    }
    #pragma unroll
    for (int mm = 1; mm < 16; mm <<= 1){
      #pragma unroll
      for (int h = 0; h < 4; ++h){
        vs[h] += __shfl_xor(vs[h], mm);
        vd[h] += __shfl_xor(vd[h], mm);
      }
    }
    if (m == 0){
      int nd = nodeBase + quad*4 + r2;
      if (nd < N){
        float2 di = dinv[nd];
        float4 mp4 = *(const float4*)(mpL + (size_t)nd*12);
        float mpv[4] = {mp4.x, mp4.y, mp4.z, mp4.w};
        float aS[4];
        #pragma unroll
        for (int h = 0; h < 4; ++h)
          aS[h] = lrelu(vs[h] + vd[h] + sCB[h]*di.x + mpv[h]);
        float4 vsv, vdv, asv;
        vsv.x=vs[0]; vsv.y=vs[1]; vsv.z=vs[2]; vsv.w=vs[3];
        vdv.x=vd[0]; vdv.y=vd[1]; vdv.z=vd[2]; vdv.w=vd[3];
        asv.x=aS[0]; asv.y=aS[1]; asv.z=aS[2]; asv.w=aS[3];
        *(float4*)(a_src + (size_t)nd*4) = vsv;
        *(float4*)(a_dst + (size_t)nd*4) = vdv;
        *(float4*)(alpha_self + (size_t)nd*4) = asv;
      }
    }
  }
}

// ---------------- MFMA GEMM: out[N,128] = A[N,K](bf16) @ W[K,128] (+bias) ----------------
template<int K, int OUTMODE, bool EPI>
__global__ __launch_bounds__(256) void mfma_lin(const unsigned short* __restrict__ A,
                                                const float* __restrict__ W,
                                                const float* __restrict__ bias,
                                                void* __restrict__ Out, void* __restrict__ Out2,
                                                int N,
                                                const float* __restrict__ attS,
                                                const float* __restrict__ attD,
                                                const float* __restrict__ cbl,
                                                const float* __restrict__ mpL,
                                                const float2* __restrict__ dinv,
                                                float* __restrict__ a_src,
                                                float* __restrict__ a_dst,
                                                float* __restrict__ alpha_self)
{
  constexpr int KP = K + 8;
  __shared__ unsigned short WT[128*KP];
  __shared__ float sAs[128], sAd[128];
  __shared__ float sCB[4];
  int tid = threadIdx.x;
  for (int i = tid; i < K*128; i += 256){
    int k = i >> 7, ch = i & 127;
    WT[ch*KP + k] = f2bf(W[i]);
  }
  if (EPI){
    if (tid < 128){ sAs[tid] = attS[tid]; sAd[tid] = attD[tid]; }
    if (tid < 4)  sCB[tid] = cbl[tid];
  }
  __syncthreads();
  int wid = tid >> 6, lane = tid & 63;
  int quad = lane >> 4, m = lane & 15;
  int nodeBase = blockIdx.x*64 + wid*16;
  int node = nodeBase + m;
  int nodeC = (node < N) ? node : 0;
  bf16x8 afr[K/32];
  #pragma unroll
  for (int kb = 0; kb < K/32; ++kb)
    afr[kb] = *(const bf16x8*)(A + (size_t)nodeC*K + kb*32 + quad*8);
  f32x4 acc[8] = {};
  #pragma unroll
  for (int t = 0; t < 8; ++t){
    #pragma unroll
    for (int kb = 0; kb < K/32; ++kb){
      bf16x8 bfr = *(const bf16x8*)&WT[(t*16 + m)*KP + kb*32 + quad*8];
      acc[t] = __builtin_amdgcn_mfma_f32_16x16x32_bf16(afr[kb], bfr, acc[t], 0, 0, 0);
    }
  }
  #pragma unroll
  for (int t = 0; t < 8; ++t){
    int ch = t*16 + m;
    float bv = bias ? bias[ch] : 0.f;
    #pragma unroll
    for (int r2 = 0; r2 < 4; ++r2){
      int nd = nodeBase + quad*4 + r2;
      if (nd < N){
        float v = acc[t][r2] + bv;
        if (OUTMODE == 0){
          ((unsigned short*)Out)[(size_t)nd*HID + ch] = f2bf(v);
        } else {
          ((float*)Out)[(size_t)nd*HID + ch] = v;
          ((unsigned short*)Out2)[(size_t)nd*HID + ch] = f2bf(v);
        }
      }
    }
  }
  if (EPI)
    att_epi(acc, m, quad, nodeBase, N, sAs, sAd, sCB,
            mpL, dinv, a_src, a_dst, alpha_self);
}

// ---------------- fused BN + ReLU + residual + GEMM (+EPI / external out) -------------
template<int OUTMODE, bool WRITEH>
__global__ __launch_bounds__(256) void bn_mfma(const unsigned short* __restrict__ hg,
                                               const float* __restrict__ hprev,
                                               const float* __restrict__ bnsum,
                                               const float* __restrict__ bnsq,
                                               const float* __restrict__ gamma,
                                               const float* __restrict__ beta,
                                               const float* __restrict__ W,
                                               const float* __restrict__ bias,
                                               void* __restrict__ Out,
                                               float* __restrict__ hout,
                                               int N, const int* __restrict__ flag,
                                               const float* __restrict__ attS,
                                               const float* __restrict__ attD,
                                               const float* __restrict__ cbl,
                                               const float* __restrict__ mpL,
                                               const float2* __restrict__ dinv,
                                               float* __restrict__ a_src,
                                               float* __restrict__ a_dst,
                                               float* __restrict__ alpha_self)
{
  constexpr int K = 128, KP = 136;
  __shared__ unsigned short WT[128*KP];
  __shared__ float sSc[128], sSh[128];
  __shared__ float sAs[128], sAd[128];
  __shared__ float sCB[4];
  int tid = threadIdx.x;
  for (int i = tid; i < K*128; i += 256){
    int k = i >> 7, ch = i & 127;
    WT[ch*KP + k] = f2bf(W[i]);
  }
  if (tid < 128){
    float s = 0.f, q = 0.f;
    #pragma unroll 8
    for (int b = 0; b < 64; ++b){
      s += bnsum[b*128 + tid];
      q += bnsq[b*128 + tid];
    }
    float mean = s / (float)N;
    float var  = fmaxf(q / (float)N - mean*mean, 0.f);
    float sc = gamma[tid] * rsqrtf(var + 1e-5f);
    sSc[tid] = sc;
    sSh[tid] = beta[tid] - mean*sc;
    if (OUTMODE == 0){ sAs[tid] = attS[tid]; sAd[tid] = attD[tid]; }
  }
  if (OUTMODE == 0){
    if (tid < 4)  sCB[tid] = cbl[tid];
  }
  __syncthreads();
  int wid = tid >> 6, lane = tid & 63;
  int quad = lane >> 4, m = lane & 15;
  int nodeBase = blockIdx.x*64 + wid*16;
  int node = nodeBase + m;
  int nodeC = (node < N) ? node : 0;
  bf16x8 afr[4];
  #pragma unroll
  for (int kb = 0; kb < 4; ++kb){
    int cbase = kb*32 + quad*8;
    uint4 gu = *(const uint4*)(hg + (size_t)nodeC*K + cbase);
    const float4* pp = (const float4*)(hprev + (size_t)nodeC*K + cbase);
    float4 p0 = pp[0], p1 = pp[1];
    unsigned gw[4] = {gu.x, gu.y, gu.z, gu.w};
    float pv[8] = {p0.x,p0.y,p0.z,p0.w,p1.x,p1.y,p1.z,p1.w};
    float r[8];
    #pragma unroll
    for (int j = 0; j < 8; ++j){
      float g = bf2f((unsigned short)((j & 1) ? (gw[j>>1] >> 16) : (gw[j>>1] & 0xffffu)));
      float t = g*sSc[cbase+j] + sSh[cbase+j];
      t = t > 0.f ? t : 0.f;
      r[j] = t + pv[j];
    }
    if (WRITEH && node < N){
      float4 o0, o1;
      o0.x=r[0]; o0.y=r[1]; o0.z=r[2]; o0.w=r[3];
      o1.x=r[4]; o1.y=r[5]; o1.z=r[6]; o1.w=r[7];
      float4* hp = (float4*)(hout + (size_t)node*K + cbase);
      hp[0] = o0; hp[1] = o1;
    }
    bf16x8 f;
    #pragma unroll
    for (int j = 0; j < 8; ++j) f[j] = (short)f2bf(r[j]);
    afr[kb] = f;
  }
  f32x4 acc[8] = {};
  #pragma unroll
  for (int t = 0; t < 8; ++t){
    #pragma unroll
    for (int kb = 0; kb < 4; ++kb){
      bf16x8 bfr = *(const bf16x8*)&WT[(t*16 + m)*KP + kb*32 + quad*8];
      acc[t] = __builtin_amdgcn_mfma_f32_16x16x32_bf16(afr[kb], bfr, acc[t], 0, 0, 0);
    }
  }
  bool f32out = (OUTMODE == 1) && (flag[0] != 0);
  #pragma unroll
  for (int t = 0; t < 8; ++t){
    int ch = t*16 + m;
    float bv = bias ? bias[ch] : 0.f;
    #pragma unroll
    for (int r2 = 0; r2 < 4; ++r2){
      int nd = nodeBase + quad*4 + r2;
      if (nd < N){
        float v = acc[t][r2] + bv;
        if (OUTMODE == 0) ((unsigned short*)Out)[(size_t)nd*HID + ch] = f2bf(v);
        else if (f32out)  ((float*)Out)[(size_t)nd*HID + ch] = v;
        else              ((unsigned short*)Out)[(size_t)nd*HID + ch] = f2bf(v);
      }
    }
  }
  if (OUTMODE == 0)
    att_epi(acc, m, quad, nodeBase, N, sAs, sAd, sCB,
            mpL, dinv, a_src, a_dst, alpha_self);
}

// ---- inline per-edge alpha: perm -> record gather -> lrelu(as + ad + proj[layer]) ----
__device__ __forceinline__ float4 edge_alpha4(const unsigned* __restrict__ recw,
                                              const int* __restrict__ perm, int pos,
                                              const float* __restrict__ a_src,
                                              float4 adn, int layer, int* src_out){
  int e0 = perm[pos];
  const unsigned* rp = recw + (size_t)e0*8;
  unsigned w0 = rp[2*layer], w1 = rp[2*layer+1];
  int s = (int)rp[6];
  float4 as4 = *(const float4*)(a_src + (size_t)s*4);
  float4 o;
  o.x = lrelu(as4.x + adn.x + bf2f((unsigned short)(w0 & 0xffffu)));
  o.y = lrelu(as4.y + adn.y + bf2f((unsigned short)(w0 >> 16)));
  o.z = lrelu(as4.z + adn.z + bf2f((unsigned short)(w1 & 0xffffu)));
  o.w = lrelu(as4.w + adn.w + bf2f((unsigned short)(w1 >> 16)));
  *src_out = s;
  return o;
}

__device__ __forceinline__ void acc2(unsigned u, float q, float& a0, float& a1){
  union { unsigned i; float f; } lo, hi;
  lo.i = u << 16; hi.i = u & 0xffff0000u;
  a0 += q*lo.f; a1 += q*hi.f;
}

// ---------------- GAT aggregation: 32 lanes/node (2 nodes/wave), fused BN stats ----
__global__ __launch_bounds__(256) void gat_agg(
    const unsigned short* __restrict__ xh,
    const uint4* __restrict__ rec, const int* __restrict__ perm,
    const int* __restrict__ row,
    const float* __restrict__ a_src, const float* __restrict__ a_dst,
    const float4* __restrict__ alpha_self,
    const float* __restrict__ bconv, unsigned short* __restrict__ hout,
    float* __restrict__ bnsumB, float* __restrict__ bnsqB,
    int N, int layer)
{
  __shared__ float sPf[8][256];      // [node][e*4+h]
  __shared__ int   sOff[8][64];
  __shared__ float sBS[8][128];      // per-node channel sums
  __shared__ float sBQ[8][128];      // per-node channel squares
  int tid = threadIdx.x;
  int wid = tid >> 6, lane = tid & 63;
  int half = lane >> 5, sl = lane & 31;
  int g = wid*2 + half;
  int n = blockIdx.x*8 + g;
  int nn = (n < N) ? n : 0;
  int r = row[nn];
  int deg = row[nn+1] - r;
  if (n >= N) deg = 0;
  const unsigned* recw = (const unsigned*)rec;

  float4 adn = *(const float4*)(a_dst + (size_t)nn*4);
  float4 aA; aA.x = aA.y = aA.z = aA.w = -1e30f;
  float4 aB; aB.x = aB.y = aB.z = aB.w = -1e30f;
  int sA = 0, sB = 0;
  if (sl < deg)      aA = edge_alpha4(recw, perm, r + sl,      a_src, adn, layer, &sA);
  if (32 + sl < deg) aB = edge_alpha4(recw, perm, r + 32 + sl, a_src, adn, layer, &sB);
  float mx0 = fmaxf(aA.x, aB.x), mx1 = fmaxf(aA.y, aB.y);
  float mx2 = fmaxf(aA.z, aB.z), mx3 = fmaxf(aA.w, aB.w);
  for (int e = 64 + sl; e < deg; e += 32){   // rare (deg>64)
    int st;
    float4 a4 = edge_alpha4(recw, perm, r + e, a_src, adn, layer, &st);
    mx0 = fmaxf(mx0, a4.x); mx1 = fmaxf(mx1, a4.y);
    mx2 = fmaxf(mx2, a4.z); mx3 = fmaxf(mx3, a4.w);
  }
  #pragma unroll
  for (int m = 1; m < 32; m <<= 1){
    mx0 = fmaxf(mx0, __shfl_xor(mx0,m)); mx1 = fmaxf(mx1, __shfl_xor(mx1,m));
    mx2 = fmaxf(mx2, __shfl_xor(mx2,m)); mx3 = fmaxf(mx3, __shfl_xor(mx3,m));
  }
  float4 sf = alpha_self[nn];
  mx0 = fmaxf(mx0, sf.x); mx1 = fmaxf(mx1, sf.y);
  mx2 = fmaxf(mx2, sf.z); mx3 = fmaxf(mx3, sf.w);

  float d0 = 0.f, d1 = 0.f, d2 = 0.f, d3 = 0.f;
  if (sl < deg){
    float4 p;
    p.x = expg(aA.x-mx0); p.y = expg(aA.y-mx1);
    p.z = expg(aA.z-mx2); p.w = expg(aA.w-mx3);
    *(float4*)&sPf[g][sl*4] = p;
    sOff[g][sl] = sA << 8;
    d0 = p.x; d1 = p.y; d2 = p.z; d3 = p.w;
  }
  if (32 + sl < deg){
    float4 p;
    p.x = expg(aB.x-mx0); p.y = expg(aB.y-mx1);
    p.z = expg(aB.z-mx2); p.w = expg(aB.w-mx3);
    *(float4*)&sPf[g][(32+sl)*4] = p;
    sOff[g][32+sl] = sB << 8;
    d0 += p.x; d1 += p.y; d2 += p.z; d3 += p.w;
  }
  for (int e = 64 + sl; e < deg; e += 32){   // rare
    int st;
    float4 a4 = edge_alpha4(recw, perm, r + e, a_src, adn, layer, &st);
    d0 += expg(a4.x-mx0); d1 += expg(a4.y-mx1);
    d2 += expg(a4.z-mx2); d3 += expg(a4.w-mx3);
  }
  #pragma unroll
  for (int m = 1; m < 32; m <<= 1){
    d0 += __shfl_xor(d0,m); d1 += __shfl_xor(d1,m); d2 += __shfl_xor(d2,m); d3 += __shfl_xor(d3,m);
  }
  float ps0 = expg(sf.x-mx0), ps1 = expg(sf.y-mx1), ps2 = expg(sf.z-mx2), ps3 = expg(sf.w-mx3);
  float i0 = 1.0f/(d0+ps0+1e-16f), i1 = 1.0f/(d1+ps1+1e-16f);
  float i2 = 1.0f/(d2+ps2+1e-16f), i3 = 1.0f/(d3+ps3+1e-16f);

  // gather: lane covers channels sl*4 .. sl*4+3; head h = sl>>3
  int h = sl >> 3;
  float mxh = h==0 ? mx0 : h==1 ? mx1 : h==2 ? mx2 : mx3;
  float ih  = h==0 ? i0  : h==1 ? i1  : h==2 ? i2  : i3;
  float psh = h==0 ? ps0 : h==1 ? ps1 : h==2 ? ps2 : ps3;
  const char* xb = (const char*)xh;
  float a0=0.f, a1=0.f, a2=0.f, a3=0.f;
  int dmin = deg < 64 ? deg : 64;
  int e = 0;
  for (; e + 4 <= dmin; e += 4){
    int oA = sOff[g][e+0], oB = sOff[g][e+1], oC = sOff[g][e+2], oD = sOff[g][e+3];
    float qA = sPf[g][(e+0)*4 + h], qB = sPf[g][(e+1)*4 + h];
    float qC = sPf[g][(e+2)*4 + h], qD = sPf[g][(e+3)*4 + h];
    uint2 xA = *(const uint2*)(xb + (size_t)oA + sl*8);
    uint2 xB = *(const uint2*)(xb + (size_t)oB + sl*8);
    uint2 xC = *(const uint2*)(xb + (size_t)oC + sl*8);
    uint2 xD = *(const uint2*)(xb + (size_t)oD + sl*8);
    acc2(xA.x, qA, a0,a1); acc2(xA.y, qA, a2,a3);
    acc2(xB.x, qB, a0,a1); acc2(xB.y, qB, a2,a3);
    acc2(xC.x, qC, a0,a1); acc2(xC.y, qC, a2,a3);
    acc2(xD.x, qD, a0,a1); acc2(xD.y, qD, a2,a3);
  }
  for (; e < dmin; ++e){
    int o = sOff[g][e];
    float q = sPf[g][e*4 + h];
    uint2 xv = *(const uint2*)(xb + (size_t)o + sl*8);
    acc2(xv.x, q, a0,a1); acc2(xv.y, q, a2,a3);
  }
  for (; e < deg; ++e){            // rare (deg>64): recompute alpha
    int st;
    float4 a4 = edge_alpha4(recw, perm, r + e, a_src, adn, layer, &st);
    float av = h==0 ? a4.x : h==1 ? a4.y : h==2 ? a4.z : a4.w;
    float q = expg(av - mxh);
    uint2 xv = *(const uint2*)(xb + (size_t)st*256 + sl*8);
    acc2(xv.x, q, a0,a1); acc2(xv.y, q, a2,a3);
  }
  float fo0=0.f, fo1=0.f, fo2=0.f, fo3=0.f;
  if (n < N){
    uint2 xn = *(const uint2*)(xb + (size_t)nn*256 + sl*8);
    acc2(xn.x, psh, a0,a1); acc2(xn.y, psh, a2,a3);
    float4 bc = *(const float4*)(bconv + layer*128 + sl*4);
    fo0 = a0*ih + bc.x; fo1 = a1*ih + bc.y;
    fo2 = a2*ih + bc.z; fo3 = a3*ih + bc.w;
    uint2 ov;
    ov.x = (unsigned)f2bf(fo0) | ((unsigned)f2bf(fo1) << 16);
    ov.y = (unsigned)f2bf(fo2) | ((unsigned)f2bf(fo3) << 16);
    *(uint2*)((char*)hout + (size_t)nn*256 + sl*8) = ov;
  }
  // fused BN stats: per-node channel partials in LDS, then banked atomics
  float4 vS; vS.x=fo0; vS.y=fo1; vS.z=fo2; vS.w=fo3;
  float4 vQ; vQ.x=fo0*fo0; vQ.y=fo1*fo1; vQ.z=fo2*fo2; vQ.w=fo3*fo3;
  *(float4*)&sBS[g][sl*4] = vS;
  *(float4*)&sBQ[g][sl*4] = vQ;
  __syncthreads();
  if (tid < 128){
    float ss = 0.f, qq = 0.f;
    #pragma unroll
    for (int k = 0; k < 8; ++k){ ss += sBS[k][tid]; qq += sBQ[k][tid]; }
    int bank = (blockIdx.x & 63) << 7;   // *128
    atomicAdd(&bnsumB[bank + tid], ss);
    atomicAdd(&bnsqB[bank + tid], qq);
  }
}

// ---------------- host ----------------
extern "C" void kernel_launch(void* const* d_in, const int* in_sizes, int n_in,
                              void* d_out, int out_size, void* d_ws, size_t ws_size,
                              hipStream_t stream)
{
  const void* x        = d_in[0];
  const int*  ei       = (const int*)d_in[1];
  const void* eattr    = d_in[2];
  int N = in_sizes[0] / 64;
  int E = in_sizes[1] / 2;

  char* p = (char*)d_ws;
  auto alloc = [&](size_t bytes)->char* {
    char* r = p; p += (bytes + 255) & ~(size_t)255; return r;
  };
  // zero-region first (one memset)
  int*   deg    = (int*)alloc((size_t)N*4);
  float* bnsumB = (float*)alloc(3*64*128*4);   // banked BN partials
  float* bnsqB  = (float*)alloc(3*64*128*4);
  size_t zbytes = (size_t)(p - (char*)deg);
  int*   dflag  = (int*)alloc(256);
  int*   row    = (int*)alloc(((size_t)N + 1)*4);
  int*   part   = (int*)alloc(1024*4);
  int*   epos   = (int*)alloc((size_t)E*4);
  uint4* rec    = (uint4*)alloc((size_t)E*32);
  int*   perm   = (int*)alloc((size_t)E*4);
  float* hA     = (float*)alloc((size_t)N*128*4);
  float* hB     = (float*)alloc((size_t)N*128*4);
  unsigned short* hGb = (unsigned short*)alloc((size_t)N*128*2);
  unsigned short* hAb = (unsigned short*)alloc((size_t)N*128*2);
  unsigned short* xhb = (unsigned short*)alloc((size_t)N*128*2);
  float* a_src  = (float*)alloc((size_t)N*4*4);
  float* a_dst  = (float*)alloc((size_t)N*4*4);
  float* alphaS = (float*)alloc((size_t)N*4*4);
  float* mproj  = (float*)alloc((size_t)N*12*4);
  float2* dinv  = (float2*)alloc((size_t)N*8);
  float* Mmat   = (float*)alloc(16*12*4);
  float* cbias  = (float*)alloc(12*4);
  unsigned short* xc  = (unsigned short*)alloc((size_t)N*64*2);
  float* wc     = (float*)alloc(130000*4);

  // canonical weight buffers (fp32)
  int   woff[14] = {0, 8192, 8320, 10368, 10496, 59648, 108800, 109184,
                    109568, 109952, 110336, 110720, 111104, 127488};
  int   wcnt[14] = {8192, 128, 2048, 128, 49152, 49152, 384, 384, 384, 384, 384, 384, 16384, 128};
  CvList L; L.n = 14;
  for (int a = 0; a < 14; ++a){ L.src[a] = d_in[3+a]; L.dst[a] = wc + woff[a]; L.cnt[a] = wcnt[a]; }
  float* cW_atom = wc + woff[0];  float* cb_atom = wc + woff[1];
  float* cW_bond = wc + woff[2];  float* cb_bond = wc + woff[3];
  float* cW_lin  = wc + woff[4];  float* cW_edge = wc + woff[5];
  float* catt_s  = wc + woff[6];  float* catt_d  = wc + woff[7];
  float* catt_e  = wc + woff[8];  float* cbconv  = wc + woff[9];
  float* cgamma  = wc + woff[10]; float* cbeta   = wc + woff[11];
  float* cW_out  = wc + woff[12]; float* cb_out  = wc + woff[13];

  hipMemsetAsync(deg, 0, zbytes, stream);
  setup<<<(E + 255)/256, 256, 0, stream>>>(L, x, xc, N*16, dflag, ei, E, deg, epos);
  int P = (N + 1023)/1024;
  scan_part_pm<<<P + 1, 256, 0, stream>>>(deg, part, N, P,
                                          cW_edge, catt_e, cW_bond, cb_bond, Mmat, cbias);
  scan_write<<<P, 256, 0, stream>>>(deg, part, row, dinv, N, E);
  proj_fill<<<(E + 255)/256, 256, 0, stream>>>(ei, E, row, epos, eattr, Mmat, rec, perm, dflag);
  mean_proj_k<<<((size_t)N*4 + 255)/256, 256, 0, stream>>>(rec, perm, row, dinv, mproj, N);

  // atom embedding: hA(fp32) + hAb(bf16) = x @ W_atom + b_atom
  mfma_lin<64, 2, false><<<(N + 63)/64, 256, 0, stream>>>(xc, cW_atom, cb_atom, hA, hAb, N,
      nullptr, nullptr, nullptr, nullptr, nullptr, nullptr, nullptr, nullptr);
  // layer-0 GEMM + attention scores + self-loop alpha
  mfma_lin<128, 0, true><<<(N + 63)/64, 256, 0, stream>>>(hAb, cW_lin, nullptr, xhb, nullptr, N,
      catt_s, catt_d, cbias, mproj, dinv, a_src, a_dst, alphaS);

  float* cur = hA; float* oth = hB;
  for (int l = 0; l < 3; ++l){
    gat_agg<<<(N + 7)/8, 256, 0, stream>>>(xhb, rec, perm, row, a_src, a_dst,
                                           (const float4*)alphaS, cbconv, hGb,
                                           bnsumB + l*8192, bnsqB + l*8192, N, l);
    if (l < 2){
      bn_mfma<0, true><<<(N + 63)/64, 256, 0, stream>>>(hGb, cur,
          bnsumB + l*8192, bnsqB + l*8192, cgamma + l*128, cbeta + l*128,
          cW_lin + (size_t)(l+1)*16384, nullptr, xhb, oth, N, dflag,
          catt_s + (l+1)*128, catt_d + (l+1)*128, cbias + (l+1)*4,
          mproj + (l+1)*4, dinv, a_src, a_dst, alphaS);
      float* t = cur; cur = oth; oth = t;
    } else {
      bn_mfma<1, false><<<(N + 63)/64, 256, 0, stream>>>(hGb, cur,
          bnsumB + l*8192, bnsqB + l*8192, cgamma + l*128, cbeta + l*128,
          cW_out, cb_out, d_out, nullptr, N, dflag,
          nullptr, nullptr, nullptr, nullptr, nullptr, nullptr, nullptr, nullptr);
    }
  }
}

// Round 13
// 425.981 us; speedup vs baseline: 1.1096x; 1.0349x over previous
//
#include <hip/hip_runtime.h>
#include <stdint.h>

#define HID 128

typedef __attribute__((ext_vector_type(8))) short bf16x8;
typedef __attribute__((ext_vector_type(4))) float f32x4;

__device__ __forceinline__ float bf2f(unsigned short u){
  union { unsigned int i; float f; } x; x.i = ((unsigned int)u) << 16; return x.f;
}
__device__ __forceinline__ unsigned short f2bf(float f){
  union { float f; unsigned int i; } x; x.f = f;
  unsigned int b = x.i;
  return (unsigned short)((b + 0x7fffu + ((b >> 16) & 1u)) >> 16);
}

// ---------------- setup: dtype flag + weight conv + x->bf16 + deg_count + edge pos ----
struct CvList {
  const void* src[16];
  float* dst[16];
  int cnt[16];
  int n;
};
__global__ __launch_bounds__(256) void setup(CvList L, const void* x,
                                             unsigned short* xc, int n4,
                                             int* __restrict__ dflag,
                                             const int* __restrict__ ei, int E,
                                             int* __restrict__ deg,
                                             int* __restrict__ epos){
  __shared__ int red[4];
  int tid = threadIdx.x;
  const unsigned short* xs = (const unsigned short*)x;
  unsigned short u = xs[tid];
  int ex = (u >> 7) & 0xFF;
  int v = ((((tid & 1) == 0) && u == 0) ? 1 : 0) | ((ex >= 140) ? 65536 : 0);
  #pragma unroll
  for (int m = 1; m < 64; m <<= 1) v += __shfl_xor(v, m);
  if ((tid & 63) == 0) red[tid >> 6] = v;
  __syncthreads();
  int tot = red[0] + red[1] + red[2] + red[3];
  bool isf32 = ((tot & 0xffff) >= 32) || ((tot >> 16) >= 8);
  if (blockIdx.x == 0 && tid == 0) dflag[0] = isf32 ? 1 : 0;
  // degree count + slot capture (whole grid)
  int e = blockIdx.x*256 + tid;
  if (e < E) epos[e] = atomicAdd(&deg[ei[E + e]], 1);
  // weights + x conversion (whole grid)
  int gstride = gridDim.x*256;
  int gid = blockIdx.x*256 + tid;
  for (int a = 0; a < L.n; ++a){
    const void* s = L.src[a];
    float* d = L.dst[a];
    int c = L.cnt[a];
    for (int i = gid; i < c; i += gstride)
      d[i] = isf32 ? ((const float*)s)[i] : bf2f(((const unsigned short*)s)[i]);
  }
  for (int i = gid; i < n4; i += gstride){
    if (isf32){
      float4 q = ((const float4*)x)[i];
      ushort4 o; o.x = f2bf(q.x); o.y = f2bf(q.y); o.z = f2bf(q.z); o.w = f2bf(q.w);
      ((ushort4*)xc)[i] = o;
    } else {
      ((ushort4*)xc)[i] = ((const ushort4*)x)[i];
    }
  }
}

// ---------------- scan_part + fused precompute_M (extra block P) ----------------
__global__ __launch_bounds__(256) void scan_part_pm(
    const int* __restrict__ deg, int* __restrict__ part, int N, int P,
    const float* __restrict__ We, const float* __restrict__ ae,
    const float* __restrict__ Wb, const float* __restrict__ bb,
    float* __restrict__ Mout, float* __restrict__ cb)
{
  __shared__ float smem[128*12];   // union: ve (6 KB) | sh (1 KB)
  int tid = threadIdx.x;
  if ((int)blockIdx.x < P){
    int* sh = (int*)smem;
    int base = blockIdx.x*1024;
    int s = 0;
    for (int i = tid; i < 1024; i += 256){ int j = base + i; if (j < N) s += deg[j]; }
    sh[tid] = s; __syncthreads();
    for (int m = 128; m > 0; m >>= 1){ if (tid < m) sh[tid] += sh[tid + m]; __syncthreads(); }
    if (tid == 0) part[blockIdx.x] = sh[0];
  } else {
    float* ve = smem;
    for (int i = tid; i < 128*12; i += 256){
      int c = i / 12, lh = i % 12; int l = lh >> 2, h = lh & 3;
      float s = 0.f;
      for (int d = 0; d < 32; ++d)
        s += We[l*16384 + c*128 + h*32 + d] * ae[l*128 + h*32 + d];
      ve[i] = s;
    }
    __syncthreads();
    for (int i = tid; i < 16*12; i += 256){
      int k = i / 12, lh = i % 12;
      float s = 0.f;
      for (int c = 0; c < 128; ++c) s += Wb[k*128 + c] * ve[c*12 + lh];
      Mout[i] = s;
    }
    for (int i = tid; i < 12; i += 256){
      float s = 0.f;
      for (int c = 0; c < 128; ++c) s += bb[c] * ve[c*12 + i];
      cb[i] = s;
    }
  }
}

// ---------------- scan_write: self top-scan (part[] holds RAW chunk sums) -------
__global__ __launch_bounds__(256) void scan_write(const int* __restrict__ deg, const int* __restrict__ part,
                                                  int* __restrict__ row, float2* __restrict__ dinv,
                                                  int N, int E){
  __shared__ int sh[256];
  int tid = threadIdx.x;
  int pb = 0;
  for (int i = tid; i < (int)blockIdx.x; i += 256) pb += part[i];
  sh[tid] = pb; __syncthreads();
  for (int m = 128; m > 0; m >>= 1){ if (tid < m) sh[tid] += sh[tid + m]; __syncthreads(); }
  int blockBase = sh[0];
  __syncthreads();

  int base = blockIdx.x*1024 + tid*4;
  int v0=0,v1=0,v2=0,v3=0;
  if (base+0 < N) v0 = deg[base+0];
  if (base+1 < N) v1 = deg[base+1];
  if (base+2 < N) v2 = deg[base+2];
  if (base+3 < N) v3 = deg[base+3];
  int s = v0+v1+v2+v3;
  sh[tid] = s; __syncthreads();
  for (int m = 1; m < 256; m <<= 1){
    int t = (tid >= m) ? sh[tid - m] : 0;
    __syncthreads();
    sh[tid] += t;
    __syncthreads();
  }
  int excl = sh[tid] - s + blockBase;
  if (base+0 < N){ row[base+0] = excl; float2 q; q.x = v0>0?1.f:0.f; q.y = 1.f/(float)(v0>0?v0:1); dinv[base+0]=q; } excl += v0;
  if (base+1 < N){ row[base+1] = excl; float2 q; q.x = v1>0?1.f:0.f; q.y = 1.f/(float)(v1>0?v1:1); dinv[base+1]=q; } excl += v1;
  if (base+2 < N){ row[base+2] = excl; float2 q; q.x = v2>0?1.f:0.f; q.y = 1.f/(float)(v2>0?v2:1); dinv[base+2]=q; } excl += v2;
  if (base+3 < N){ row[base+3] = excl; float2 q; q.x = v3>0?1.f:0.f; q.y = 1.f/(float)(v3>0?v3:1); dinv[base+3]=q; }
  if (blockIdx.x == 0 && tid == 0) row[N] = E;
}

// ---------------- proj_fill: per-edge 12 projections (bf16), NO ATOMIC (epos from setup) ----
__global__ __launch_bounds__(256) void proj_fill(const int* __restrict__ ei, int E,
                                                 const int* __restrict__ row,
                                                 const int* __restrict__ epos,
                                                 const void* __restrict__ eattr,
                                                 const float* __restrict__ Mmat,
                                                 uint4* __restrict__ rec, int* __restrict__ perm,
                                                 const int* __restrict__ flag){
  __shared__ float sM[16][12];
  int tid = threadIdx.x;
  if (tid < 192) sM[tid/12][tid%12] = Mmat[tid];
  __syncthreads();
  int e = blockIdx.x*256 + tid;
  if (e >= E) return;
  int s = ei[e], d = ei[E + e];
  float v[16];
  if (flag[0]){
    const float4* pp = (const float4*)((const float*)eattr + (size_t)e*16);
    float4 a = pp[0], b = pp[1], c = pp[2], dd = pp[3];
    v[0]=a.x; v[1]=a.y; v[2]=a.z; v[3]=a.w;
    v[4]=b.x; v[5]=b.y; v[6]=b.z; v[7]=b.w;
    v[8]=c.x; v[9]=c.y; v[10]=c.z; v[11]=c.w;
    v[12]=dd.x; v[13]=dd.y; v[14]=dd.z; v[15]=dd.w;
  } else {
    const uint4* pp = (const uint4*)((const unsigned short*)eattr + (size_t)e*16);
    uint4 a = pp[0], b = pp[1];
    unsigned w[8] = {a.x,a.y,a.z,a.w,b.x,b.y,b.z,b.w};
    #pragma unroll
    for (int j = 0; j < 8; ++j){
      v[2*j]   = bf2f((unsigned short)(w[j] & 0xffffu));
      v[2*j+1] = bf2f((unsigned short)(w[j] >> 16));
    }
  }
  float p[12];
  #pragma unroll
  for (int j = 0; j < 12; ++j){
    float acc = 0.f;
    #pragma unroll
    for (int k = 0; k < 16; ++k) acc += v[k]*sM[k][j];
    p[j] = acc;
  }
  uint4 q0, q1;
  q0.x = (unsigned)f2bf(p[0])  | ((unsigned)f2bf(p[1])  << 16);
  q0.y = (unsigned)f2bf(p[2])  | ((unsigned)f2bf(p[3])  << 16);
  q0.z = (unsigned)f2bf(p[4])  | ((unsigned)f2bf(p[5])  << 16);
  q0.w = (unsigned)f2bf(p[6])  | ((unsigned)f2bf(p[7])  << 16);
  q1.x = (unsigned)f2bf(p[8])  | ((unsigned)f2bf(p[9])  << 16);
  q1.y = (unsigned)f2bf(p[10]) | ((unsigned)f2bf(p[11]) << 16);
  q1.z = (unsigned)s; q1.w = (unsigned)d;
  rec[(size_t)e*2]   = q0;   // coalesced, edge order
  rec[(size_t)e*2+1] = q1;
  perm[row[d] + epos[e]] = e;   // 4 B scattered store, no RMW
}

// ---------------- per-node mean of projected edge terms: 4 lanes/node ----------
__global__ __launch_bounds__(256) void mean_proj_k(const uint4* __restrict__ rec,
                                                   const int* __restrict__ perm,
                                                   const int* __restrict__ row,
                                                   const float2* __restrict__ dinv,
                                                   float* __restrict__ mp, int N){
  int idx = blockIdx.x*256 + threadIdx.x;
  int n = idx >> 2, q = idx & 3;
  if (n >= N) return;
  int r = row[n], deg = row[n+1] - r;
  float acc[12] = {};
  for (int e = q; e < deg; e += 4){
    int ed = perm[r + e];
    uint4 a = rec[(size_t)ed*2];
    uint2 b = *(const uint2*)(rec + (size_t)ed*2 + 1);
    unsigned w[6] = {a.x,a.y,a.z,a.w,b.x,b.y};
    #pragma unroll
    for (int j = 0; j < 6; ++j){
      acc[2*j]   += bf2f((unsigned short)(w[j] & 0xffffu));
      acc[2*j+1] += bf2f((unsigned short)(w[j] >> 16));
    }
  }
  #pragma unroll
  for (int m = 1; m < 4; m <<= 1){
    #pragma unroll
    for (int j = 0; j < 12; ++j) acc[j] += __shfl_xor(acc[j], m);
  }
  if (q == 0){
    float inv = dinv[n].x > 0.f ? dinv[n].y : 1.f;
    float* op = mp + (size_t)n*12;
    float4 o0, o1, o2;
    o0.x=acc[0]*inv; o0.y=acc[1]*inv; o0.z=acc[2]*inv; o0.w=acc[3]*inv;
    o1.x=acc[4]*inv; o1.y=acc[5]*inv; o1.z=acc[6]*inv; o1.w=acc[7]*inv;
    o2.x=acc[8]*inv; o2.y=acc[9]*inv; o2.z=acc[10]*inv; o2.w=acc[11]*inv;
    *(float4*)(op)   = o0;
    *(float4*)(op+4) = o1;
    *(float4*)(op+8) = o2;
  }
}

__device__ __forceinline__ float lrelu(float x){ return x > 0.f ? x : 0.2f*x; }
__device__ __forceinline__ float expg(float x){ return __expf(fminf(x, 0.f)); }

// shared EPI: attention scores + self-loop alpha, from acc[8] C-fragments
template<typename ACC>
__device__ __forceinline__ void att_epi(const ACC* acc, int m, int quad, int nodeBase, int N,
                                        const float* sAs, const float* sAd,
                                        const float* sCB,
                                        const float* __restrict__ mpL,
                                        const float2* __restrict__ dinv,
                                        float* __restrict__ a_src,
                                        float* __restrict__ a_dst,
                                        float* __restrict__ alpha_self)
{
  #pragma unroll
  for (int r2 = 0; r2 < 4; ++r2){
    float vs[4], vd[4];
    #pragma unroll
    for (int h = 0; h < 4; ++h){
      int c0 = (2*h)*16 + m, c1 = (2*h+1)*16 + m;
      vs[h] = acc[2*h][r2]*sAs[c0] + acc[2*h+1][r2]*sAs[c1];
      vd[h] = acc[2*h][r2]*sAd[c0] + acc[2*h+1][r2]*sAd[c1];
    }
    #pragma unroll
    for (int mm = 1; mm < 16; mm <<= 1){
      #pragma unroll
      for (int h = 0; h < 4; ++h){
        vs[h] += __shfl_xor(vs[h], mm);
        vd[h] += __shfl_xor(vd[h], mm);
      }
    }
    if (m == 0){
      int nd = nodeBase + quad*4 + r2;
      if (nd < N){
        float2 di = dinv[nd];
        float4 mp4 = *(const float4*)(mpL + (size_t)nd*12);
        float mpv[4] = {mp4.x, mp4.y, mp4.z, mp4.w};
        float aS[4];
        #pragma unroll
        for (int h = 0; h < 4; ++h)
          aS[h] = lrelu(vs[h] + vd[h] + sCB[h]*di.x + mpv[h]);
        float4 vsv, vdv, asv;
        vsv.x=vs[0]; vsv.y=vs[1]; vsv.z=vs[2]; vsv.w=vs[3];
        vdv.x=vd[0]; vdv.y=vd[1]; vdv.z=vd[2]; vdv.w=vd[3];
        asv.x=aS[0]; asv.y=aS[1]; asv.z=aS[2]; asv.w=aS[3];
        *(float4*)(a_src + (size_t)nd*4) = vsv;
        *(float4*)(a_dst + (size_t)nd*4) = vdv;
        *(float4*)(alpha_self + (size_t)nd*4) = asv;
      }
    }
  }
}

// ---------------- MFMA GEMM: out[N,128] = A[N,K](bf16) @ W[K,128] (+bias), bf16 out ----
template<int K, bool EPI>
__global__ __launch_bounds__(256) void mfma_lin(const unsigned short* __restrict__ A,
                                                const float* __restrict__ W,
                                                const float* __restrict__ bias,
                                                void* __restrict__ Out,
                                                int N,
                                                const float* __restrict__ attS,
                                                const float* __restrict__ attD,
                                                const float* __restrict__ cbl,
                                                const float* __restrict__ mpL,
                                                const float2* __restrict__ dinv,
                                                float* __restrict__ a_src,
                                                float* __restrict__ a_dst,
                                                float* __restrict__ alpha_self)
{
  constexpr int KP = K + 8;
  __shared__ unsigned short WT[128*KP];
  __shared__ float sAs[128], sAd[128];
  __shared__ float sCB[4];
  int tid = threadIdx.x;
  for (int i = tid; i < K*128; i += 256){
    int k = i >> 7, ch = i & 127;
    WT[ch*KP + k] = f2bf(W[i]);
  }
  if (EPI){
    if (tid < 128){ sAs[tid] = attS[tid]; sAd[tid] = attD[tid]; }
    if (tid < 4)  sCB[tid] = cbl[tid];
  }
  __syncthreads();
  int wid = tid >> 6, lane = tid & 63;
  int quad = lane >> 4, m = lane & 15;
  int nodeBase = blockIdx.x*64 + wid*16;
  int node = nodeBase + m;
  int nodeC = (node < N) ? node : 0;
  bf16x8 afr[K/32];
  #pragma unroll
  for (int kb = 0; kb < K/32; ++kb)
    afr[kb] = *(const bf16x8*)(A + (size_t)nodeC*K + kb*32 + quad*8);
  f32x4 acc[8] = {};
  #pragma unroll
  for (int t = 0; t < 8; ++t){
    #pragma unroll
    for (int kb = 0; kb < K/32; ++kb){
      bf16x8 bfr = *(const bf16x8*)&WT[(t*16 + m)*KP + kb*32 + quad*8];
      acc[t] = __builtin_amdgcn_mfma_f32_16x16x32_bf16(afr[kb], bfr, acc[t], 0, 0, 0);
    }
  }
  #pragma unroll
  for (int t = 0; t < 8; ++t){
    int ch = t*16 + m;
    float bv = bias ? bias[ch] : 0.f;
    #pragma unroll
    for (int r2 = 0; r2 < 4; ++r2){
      int nd = nodeBase + quad*4 + r2;
      if (nd < N){
        float v = acc[t][r2] + bv;
        ((unsigned short*)Out)[(size_t)nd*HID + ch] = f2bf(v);
      }
    }
  }
  if (EPI)
    att_epi(acc, m, quad, nodeBase, N, sAs, sAd, sCB,
            mpL, dinv, a_src, a_dst, alpha_self);
}

// ---------------- fused BN + ReLU + residual + GEMM (+EPI / external out) -------------
// hg bf16 (GAT out); hprev bf16 residual; hout bf16 (identical to MFMA A-operand).
// OUTMODE 0: bf16 xh out + EPI + bf16 h out; 1: external out
template<int OUTMODE, bool WRITEH>
__global__ __launch_bounds__(256) void bn_mfma(const unsigned short* __restrict__ hg,
                                               const unsigned short* __restrict__ hprev,
                                               const float* __restrict__ bnsum,
                                               const float* __restrict__ bnsq,
                                               const float* __restrict__ gamma,
                                               const float* __restrict__ beta,
                                               const float* __restrict__ W,
                                               const float* __restrict__ bias,
                                               void* __restrict__ Out,
                                               unsigned short* __restrict__ hout,
                                               int N, const int* __restrict__ flag,
                                               const float* __restrict__ attS,
                                               const float* __restrict__ attD,
                                               const float* __restrict__ cbl,
                                               const float* __restrict__ mpL,
                                               const float2* __restrict__ dinv,
                                               float* __restrict__ a_src,
                                               float* __restrict__ a_dst,
                                               float* __restrict__ alpha_self)
{
  constexpr int K = 128, KP = 136;
  __shared__ unsigned short WT[128*KP];
  __shared__ float sSc[128], sSh[128];
  __shared__ float sAs[128], sAd[128];
  __shared__ float sCB[4];
  int tid = threadIdx.x;
  for (int i = tid; i < K*128; i += 256){
    int k = i >> 7, ch = i & 127;
    WT[ch*KP + k] = f2bf(W[i]);
  }
  if (tid < 128){
    float s = 0.f, q = 0.f;
    #pragma unroll 8
    for (int b = 0; b < 64; ++b){
      s += bnsum[b*128 + tid];
      q += bnsq[b*128 + tid];
    }
    float mean = s / (float)N;
    float var  = fmaxf(q / (float)N - mean*mean, 0.f);
    float sc = gamma[tid] * rsqrtf(var + 1e-5f);
    sSc[tid] = sc;
    sSh[tid] = beta[tid] - mean*sc;
    if (OUTMODE == 0){ sAs[tid] = attS[tid]; sAd[tid] = attD[tid]; }
  }
  if (OUTMODE == 0){
    if (tid < 4)  sCB[tid] = cbl[tid];
  }
  __syncthreads();
  int wid = tid >> 6, lane = tid & 63;
  int quad = lane >> 4, m = lane & 15;
  int nodeBase = blockIdx.x*64 + wid*16;
  int node = nodeBase + m;
  int nodeC = (node < N) ? node : 0;
  bf16x8 afr[4];
  #pragma unroll
  for (int kb = 0; kb < 4; ++kb){
    int cbase = kb*32 + quad*8;
    uint4 gu = *(const uint4*)(hg + (size_t)nodeC*K + cbase);
    uint4 pu = *(const uint4*)(hprev + (size_t)nodeC*K + cbase);
    unsigned gw[4] = {gu.x, gu.y, gu.z, gu.w};
    unsigned pw[4] = {pu.x, pu.y, pu.z, pu.w};
    float r[8];
    #pragma unroll
    for (int j = 0; j < 8; ++j){
      float g = bf2f((unsigned short)((j & 1) ? (gw[j>>1] >> 16) : (gw[j>>1] & 0xffffu)));
      float pv = bf2f((unsigned short)((j & 1) ? (pw[j>>1] >> 16) : (pw[j>>1] & 0xffffu)));
      float t = g*sSc[cbase+j] + sSh[cbase+j];
      t = t > 0.f ? t : 0.f;
      r[j] = t + pv;
    }
    bf16x8 f;
    #pragma unroll
    for (int j = 0; j < 8; ++j) f[j] = (short)f2bf(r[j]);
    afr[kb] = f;
    if (WRITEH && node < N)
      *(bf16x8*)(hout + (size_t)node*K + cbase) = f;   // residual == MFMA operand
  }
  f32x4 acc[8] = {};
  #pragma unroll
  for (int t = 0; t < 8; ++t){
    #pragma unroll
    for (int kb = 0; kb < 4; ++kb){
      bf16x8 bfr = *(const bf16x8*)&WT[(t*16 + m)*KP + kb*32 + quad*8];
      acc[t] = __builtin_amdgcn_mfma_f32_16x16x32_bf16(afr[kb], bfr, acc[t], 0, 0, 0);
    }
  }
  bool f32out = (OUTMODE == 1) && (flag[0] != 0);
  #pragma unroll
  for (int t = 0; t < 8; ++t){
    int ch = t*16 + m;
    float bv = bias ? bias[ch] : 0.f;
    #pragma unroll
    for (int r2 = 0; r2 < 4; ++r2){
      int nd = nodeBase + quad*4 + r2;
      if (nd < N){
        float v = acc[t][r2] + bv;
        if (OUTMODE == 0) ((unsigned short*)Out)[(size_t)nd*HID + ch] = f2bf(v);
        else if (f32out)  ((float*)Out)[(size_t)nd*HID + ch] = v;
        else              ((unsigned short*)Out)[(size_t)nd*HID + ch] = f2bf(v);
      }
    }
  }
  if (OUTMODE == 0)
    att_epi(acc, m, quad, nodeBase, N, sAs, sAd, sCB,
            mpL, dinv, a_src, a_dst, alpha_self);
}

// ---- inline per-edge alpha: perm -> record gather -> lrelu(as + ad + proj[layer]) ----
__device__ __forceinline__ float4 edge_alpha4(const unsigned* __restrict__ recw,
                                              const int* __restrict__ perm, int pos,
                                              const float* __restrict__ a_src,
                                              float4 adn, int layer, int* src_out){
  int e0 = perm[pos];
  const unsigned* rp = recw + (size_t)e0*8;
  unsigned w0 = rp[2*layer], w1 = rp[2*layer+1];
  int s = (int)rp[6];
  float4 as4 = *(const float4*)(a_src + (size_t)s*4);
  float4 o;
  o.x = lrelu(as4.x + adn.x + bf2f((unsigned short)(w0 & 0xffffu)));
  o.y = lrelu(as4.y + adn.y + bf2f((unsigned short)(w0 >> 16)));
  o.z = lrelu(as4.z + adn.z + bf2f((unsigned short)(w1 & 0xffffu)));
  o.w = lrelu(as4.w + adn.w + bf2f((unsigned short)(w1 >> 16)));
  *src_out = s;
  return o;
}

__device__ __forceinline__ void acc2(unsigned u, float q, float& a0, float& a1){
  union { unsigned i; float f; } lo, hi;
  lo.i = u << 16; hi.i = u & 0xffff0000u;
  a0 += q*lo.f; a1 += q*hi.f;
}

// ---------------- GAT aggregation: 32 lanes/node (2 nodes/wave), fused BN stats ----
__global__ __launch_bounds__(256) void gat_agg(
    const unsigned short* __restrict__ xh,
    const uint4* __restrict__ rec, const int* __restrict__ perm,
    const int* __restrict__ row,
    const float* __restrict__ a_src, const float* __restrict__ a_dst,
    const float4* __restrict__ alpha_self,
    const float* __restrict__ bconv, unsigned short* __restrict__ hout,
    float* __restrict__ bnsumB, float* __restrict__ bnsqB,
    int N, int layer)
{
  __shared__ float sPf[8][256];      // [node][e*4+h]
  __shared__ int   sOff[8][64];
  __shared__ float sBS[8][128];      // per-node channel sums
  __shared__ float sBQ[8][128];      // per-node channel squares
  int tid = threadIdx.x;
  int wid = tid >> 6, lane = tid & 63;
  int half = lane >> 5, sl = lane & 31;
  int g = wid*2 + half;
  int n = blockIdx.x*8 + g;
  int nn = (n < N) ? n : 0;
  int r = row[nn];
  int deg = row[nn+1] - r;
  if (n >= N) deg = 0;
  const unsigned* recw = (const unsigned*)rec;

  float4 adn = *(const float4*)(a_dst + (size_t)nn*4);
  float4 aA; aA.x = aA.y = aA.z = aA.w = -1e30f;
  float4 aB; aB.x = aB.y = aB.z = aB.w = -1e30f;
  int sA = 0, sB = 0;
  if (sl < deg)      aA = edge_alpha4(recw, perm, r + sl,      a_src, adn, layer, &sA);
  if (32 + sl < deg) aB = edge_alpha4(recw, perm, r + 32 + sl, a_src, adn, layer, &sB);
  float mx0 = fmaxf(aA.x, aB.x), mx1 = fmaxf(aA.y, aB.y);
  float mx2 = fmaxf(aA.z, aB.z), mx3 = fmaxf(aA.w, aB.w);
  for (int e = 64 + sl; e < deg; e += 32){   // rare (deg>64)
    int st;
    float4 a4 = edge_alpha4(recw, perm, r + e, a_src, adn, layer, &st);
    mx0 = fmaxf(mx0, a4.x); mx1 = fmaxf(mx1, a4.y);
    mx2 = fmaxf(mx2, a4.z); mx3 = fmaxf(mx3, a4.w);
  }
  #pragma unroll
  for (int m = 1; m < 32; m <<= 1){
    mx0 = fmaxf(mx0, __shfl_xor(mx0,m)); mx1 = fmaxf(mx1, __shfl_xor(mx1,m));
    mx2 = fmaxf(mx2, __shfl_xor(mx2,m)); mx3 = fmaxf(mx3, __shfl_xor(mx3,m));
  }
  float4 sf = alpha_self[nn];
  mx0 = fmaxf(mx0, sf.x); mx1 = fmaxf(mx1, sf.y);
  mx2 = fmaxf(mx2, sf.z); mx3 = fmaxf(mx3, sf.w);

  float d0 = 0.f, d1 = 0.f, d2 = 0.f, d3 = 0.f;
  if (sl < deg){
    float4 p;
    p.x = expg(aA.x-mx0); p.y = expg(aA.y-mx1);
    p.z = expg(aA.z-mx2); p.w = expg(aA.w-mx3);
    *(float4*)&sPf[g][sl*4] = p;
    sOff[g][sl] = sA << 8;
    d0 = p.x; d1 = p.y; d2 = p.z; d3 = p.w;
  }
  if (32 + sl < deg){
    float4 p;
    p.x = expg(aB.x-mx0); p.y = expg(aB.y-mx1);
    p.z = expg(aB.z-mx2); p.w = expg(aB.w-mx3);
    *(float4*)&sPf[g][(32+sl)*4] = p;
    sOff[g][32+sl] = sB << 8;
    d0 += p.x; d1 += p.y; d2 += p.z; d3 += p.w;
  }
  for (int e = 64 + sl; e < deg; e += 32){   // rare
    int st;
    float4 a4 = edge_alpha4(recw, perm, r + e, a_src, adn, layer, &st);
    d0 += expg(a4.x-mx0); d1 += expg(a4.y-mx1);
    d2 += expg(a4.z-mx2); d3 += expg(a4.w-mx3);
  }
  #pragma unroll
  for (int m = 1; m < 32; m <<= 1){
    d0 += __shfl_xor(d0,m); d1 += __shfl_xor(d1,m); d2 += __shfl_xor(d2,m); d3 += __shfl_xor(d3,m);
  }
  float ps0 = expg(sf.x-mx0), ps1 = expg(sf.y-mx1), ps2 = expg(sf.z-mx2), ps3 = expg(sf.w-mx3);
  float i0 = 1.0f/(d0+ps0+1e-16f), i1 = 1.0f/(d1+ps1+1e-16f);
  float i2 = 1.0f/(d2+ps2+1e-16f), i3 = 1.0f/(d3+ps3+1e-16f);

  // gather: lane covers channels sl*4 .. sl*4+3; head h = sl>>3
  int h = sl >> 3;
  float mxh = h==0 ? mx0 : h==1 ? mx1 : h==2 ? mx2 : mx3;
  float ih  = h==0 ? i0  : h==1 ? i1  : h==2 ? i2  : i3;
  float psh = h==0 ? ps0 : h==1 ? ps1 : h==2 ? ps2 : ps3;
  const char* xb = (const char*)xh;
  float a0=0.f, a1=0.f, a2=0.f, a3=0.f;
  int dmin = deg < 64 ? deg : 64;
  int e = 0;
  for (; e + 4 <= dmin; e += 4){
    int oA = sOff[g][e+0], oB = sOff[g][e+1], oC = sOff[g][e+2], oD = sOff[g][e+3];
    float qA = sPf[g][(e+0)*4 + h], qB = sPf[g][(e+1)*4 + h];
    float qC = sPf[g][(e+2)*4 + h], qD = sPf[g][(e+3)*4 + h];
    uint2 xA = *(const uint2*)(xb + (size_t)oA + sl*8);
    uint2 xB = *(const uint2*)(xb + (size_t)oB + sl*8);
    uint2 xC = *(const uint2*)(xb + (size_t)oC + sl*8);
    uint2 xD = *(const uint2*)(xb + (size_t)oD + sl*8);
    acc2(xA.x, qA, a0,a1); acc2(xA.y, qA, a2,a3);
    acc2(xB.x, qB, a0,a1); acc2(xB.y, qB, a2,a3);
    acc2(xC.x, qC, a0,a1); acc2(xC.y, qC, a2,a3);
    acc2(xD.x, qD, a0,a1); acc2(xD.y, qD, a2,a3);
  }
  for (; e < dmin; ++e){
    int o = sOff[g][e];
    float q = sPf[g][e*4 + h];
    uint2 xv = *(const uint2*)(xb + (size_t)o + sl*8);
    acc2(xv.x, q, a0,a1); acc2(xv.y, q, a2,a3);
  }
  for (; e < deg; ++e){            // rare (deg>64): recompute alpha
    int st;
    float4 a4 = edge_alpha4(recw, perm, r + e, a_src, adn, layer, &st);
    float av = h==0 ? a4.x : h==1 ? a4.y : h==2 ? a4.z : a4.w;
    float q = expg(av - mxh);
    uint2 xv = *(const uint2*)(xb + (size_t)st*256 + sl*8);
    acc2(xv.x, q, a0,a1); acc2(xv.y, q, a2,a3);
  }
  float fo0=0.f, fo1=0.f, fo2=0.f, fo3=0.f;
  if (n < N){
    uint2 xn = *(const uint2*)(xb + (size_t)nn*256 + sl*8);
    acc2(xn.x, psh, a0,a1); acc2(xn.y, psh, a2,a3);
    float4 bc = *(const float4*)(bconv + layer*128 + sl*4);
    fo0 = a0*ih + bc.x; fo1 = a1*ih + bc.y;
    fo2 = a2*ih + bc.z; fo3 = a3*ih + bc.w;
    uint2 ov;
    ov.x = (unsigned)f2bf(fo0) | ((unsigned)f2bf(fo1) << 16);
    ov.y = (unsigned)f2bf(fo2) | ((unsigned)f2bf(fo3) << 16);
    *(uint2*)((char*)hout + (size_t)nn*256 + sl*8) = ov;
  }
  // fused BN stats: per-node channel partials in LDS, then banked atomics
  float4 vS; vS.x=fo0; vS.y=fo1; vS.z=fo2; vS.w=fo3;
  float4 vQ; vQ.x=fo0*fo0; vQ.y=fo1*fo1; vQ.z=fo2*fo2; vQ.w=fo3*fo3;
  *(float4*)&sBS[g][sl*4] = vS;
  *(float4*)&sBQ[g][sl*4] = vQ;
  __syncthreads();
  if (tid < 128){
    float ss = 0.f, qq = 0.f;
    #pragma unroll
    for (int k = 0; k < 8; ++k){ ss += sBS[k][tid]; qq += sBQ[k][tid]; }
    int bank = (blockIdx.x & 63) << 7;   // *128
    atomicAdd(&bnsumB[bank + tid], ss);
    atomicAdd(&bnsqB[bank + tid], qq);
  }
}

// ---------------- host ----------------
extern "C" void kernel_launch(void* const* d_in, const int* in_sizes, int n_in,
                              void* d_out, int out_size, void* d_ws, size_t ws_size,
                              hipStream_t stream)
{
  const void* x        = d_in[0];
  const int*  ei       = (const int*)d_in[1];
  const void* eattr    = d_in[2];
  int N = in_sizes[0] / 64;
  int E = in_sizes[1] / 2;

  char* p = (char*)d_ws;
  auto alloc = [&](size_t bytes)->char* {
    char* r = p; p += (bytes + 255) & ~(size_t)255; return r;
  };
  // zero-region first (one memset)
  int*   deg    = (int*)alloc((size_t)N*4);
  float* bnsumB = (float*)alloc(3*64*128*4);   // banked BN partials
  float* bnsqB  = (float*)alloc(3*64*128*4);
  size_t zbytes = (size_t)(p - (char*)deg);
  int*   dflag  = (int*)alloc(256);
  int*   row    = (int*)alloc(((size_t)N + 1)*4);
  int*   part   = (int*)alloc(1024*4);
  int*   epos   = (int*)alloc((size_t)E*4);
  uint4* rec    = (uint4*)alloc((size_t)E*32);
  int*   perm   = (int*)alloc((size_t)E*4);
  unsigned short* hAb = (unsigned short*)alloc((size_t)N*128*2);  // residual cur (bf16)
  unsigned short* hBb = (unsigned short*)alloc((size_t)N*128*2);  // residual oth (bf16)
  unsigned short* hGb = (unsigned short*)alloc((size_t)N*128*2);
  unsigned short* xhb = (unsigned short*)alloc((size_t)N*128*2);
  float* a_src  = (float*)alloc((size_t)N*4*4);
  float* a_dst  = (float*)alloc((size_t)N*4*4);
  float* alphaS = (float*)alloc((size_t)N*4*4);
  float* mproj  = (float*)alloc((size_t)N*12*4);
  float2* dinv  = (float2*)alloc((size_t)N*8);
  float* Mmat   = (float*)alloc(16*12*4);
  float* cbias  = (float*)alloc(12*4);
  unsigned short* xc  = (unsigned short*)alloc((size_t)N*64*2);
  float* wc     = (float*)alloc(130000*4);

  // canonical weight buffers (fp32)
  int   woff[14] = {0, 8192, 8320, 10368, 10496, 59648, 108800, 109184,
                    109568, 109952, 110336, 110720, 111104, 127488};
  int   wcnt[14] = {8192, 128, 2048, 128, 49152, 49152, 384, 384, 384, 384, 384, 384, 16384, 128};
  CvList L; L.n = 14;
  for (int a = 0; a < 14; ++a){ L.src[a] = d_in[3+a]; L.dst[a] = wc + woff[a]; L.cnt[a] = wcnt[a]; }
  float* cW_atom = wc + woff[0];  float* cb_atom = wc + woff[1];
  float* cW_bond = wc + woff[2];  float* cb_bond = wc + woff[3];
  float* cW_lin  = wc + woff[4];  float* cW_edge = wc + woff[5];
  float* catt_s  = wc + woff[6];  float* catt_d  = wc + woff[7];
  float* catt_e  = wc + woff[8];  float* cbconv  = wc + woff[9];
  float* cgamma  = wc + woff[10]; float* cbeta   = wc + woff[11];
  float* cW_out  = wc + woff[12]; float* cb_out  = wc + woff[13];

  hipMemsetAsync(deg, 0, zbytes, stream);
  setup<<<(E + 255)/256, 256, 0, stream>>>(L, x, xc, N*16, dflag, ei, E, deg, epos);
  int P = (N + 1023)/1024;
  scan_part_pm<<<P + 1, 256, 0, stream>>>(deg, part, N, P,
                                          cW_edge, catt_e, cW_bond, cb_bond, Mmat, cbias);
  scan_write<<<P, 256, 0, stream>>>(deg, part, row, dinv, N, E);
  proj_fill<<<(E + 255)/256, 256, 0, stream>>>(ei, E, row, epos, eattr, Mmat, rec, perm, dflag);
  mean_proj_k<<<((size_t)N*4 + 255)/256, 256, 0, stream>>>(rec, perm, row, dinv, mproj, N);

  // atom embedding: hAb(bf16) = x @ W_atom + b_atom
  mfma_lin<64, false><<<(N + 63)/64, 256, 0, stream>>>(xc, cW_atom, cb_atom, hAb, N,
      nullptr, nullptr, nullptr, nullptr, nullptr, nullptr, nullptr, nullptr);
  // layer-0 GEMM + attention scores + self-loop alpha
  mfma_lin<128, true><<<(N + 63)/64, 256, 0, stream>>>(hAb, cW_lin, nullptr, xhb, N,
      catt_s, catt_d, cbias, mproj, dinv, a_src, a_dst, alphaS);

  unsigned short* cur = hAb; unsigned short* oth = hBb;
  for (int l = 0; l < 3; ++l){
    gat_agg<<<(N + 7)/8, 256, 0, stream>>>(xhb, rec, perm, row, a_src, a_dst,
                                           (const float4*)alphaS, cbconv, hGb,
                                           bnsumB + l*8192, bnsqB + l*8192, N, l);
    if (l < 2){
      bn_mfma<0, true><<<(N + 63)/64, 256, 0, stream>>>(hGb, cur,
          bnsumB + l*8192, bnsqB + l*8192, cgamma + l*128, cbeta + l*128,
          cW_lin + (size_t)(l+1)*16384, nullptr, xhb, oth, N, dflag,
          catt_s + (l+1)*128, catt_d + (l+1)*128, cbias + (l+1)*4,
          mproj + (l+1)*4, dinv, a_src, a_dst, alphaS);
      unsigned short* t = cur; cur = oth; oth = t;
    } else {
      bn_mfma<1, false><<<(N + 63)/64, 256, 0, stream>>>(hGb, cur,
          bnsumB + l*8192, bnsqB + l*8192, cgamma + l*128, cbeta + l*128,
          cW_out, cb_out, d_out, nullptr, N, dflag,
          nullptr, nullptr, nullptr, nullptr, nullptr, nullptr, nullptr, nullptr);
    }
  }
}